// Round 1
// baseline (1764.989 us; speedup 1.0000x reference)
//
#include <hip/hip_runtime.h>
#include <hip/hip_bf16.h>

#define F_IN   74
#define HDIM   256
#define NHEAD  8
#define HEADD  32
#define NLAYER 4
#define SLOPE  0.2f
#define EPSN   1e-5f

__device__ __forceinline__ float bf2f(unsigned short u){
  union { unsigned int i; float f; } x; x.i = ((unsigned int)u) << 16; return x.f;
}
__device__ __forceinline__ unsigned short f2bf(float f){
  union { float f; unsigned int i; } x; x.f = f;
  unsigned int u = x.i;
  return (unsigned short)((u + 0x7FFFu + ((u >> 16) & 1u)) >> 16);
}

// ---------------- CSR build (dst-grouped) ----------------
__global__ void k_hist(const int* __restrict__ dst, int* __restrict__ deg, int e){
  int i = blockIdx.x * 256 + threadIdx.x;
  if (i < e) atomicAdd(&deg[dst[i]], 1);
}

// exclusive scan of (deg[i]+1) -> rowp[0..n], single block, chunked
__global__ __launch_bounds__(256) void k_scan(const int* __restrict__ deg,
                                              int* __restrict__ rowp, int n){
  __shared__ int wsum[4];
  __shared__ int carry;
  const int tid = threadIdx.x, lane = tid & 63, wid = tid >> 6;
  if (tid == 0) carry = 0;
  __syncthreads();
  for (int base = 0; base < n; base += 256){
    int i = base + tid;
    int v = (i < n) ? (deg[i] + 1) : 0;   // +1 self-loop
    int xv = v;
    #pragma unroll
    for (int off = 1; off < 64; off <<= 1){
      int t = __shfl_up(xv, off);
      if (lane >= off) xv += t;
    }
    if (lane == 63) wsum[wid] = xv;
    __syncthreads();
    int woff = 0, total = 0;
    #pragma unroll
    for (int w = 0; w < 4; ++w){
      int s = wsum[w];
      total += s;
      if (w < wid) woff += s;
    }
    if (i < n) rowp[i] = carry + woff + xv - v;
    __syncthreads();
    if (tid == 0) carry += total;
    __syncthreads();
  }
  if (threadIdx.x == 0) rowp[n] = carry;
}

__global__ void k_copy(const int* __restrict__ a, int* __restrict__ b, int n){
  int i = blockIdx.x * 256 + threadIdx.x;
  if (i < n) b[i] = a[i];
}
__global__ void k_fill(const int* __restrict__ src, const int* __restrict__ dst,
                       int* __restrict__ cur, int* __restrict__ csr, int e){
  int i = blockIdx.x * 256 + threadIdx.x;
  if (i < e){
    int p = atomicAdd(&cur[dst[i]], 1);
    csr[p] = src[i];
  }
}
__global__ void k_fillself(int* __restrict__ cur, int* __restrict__ csr, int n){
  int i = blockIdx.x * 256 + threadIdx.x;
  if (i < n){
    int p = atomicAdd(&cur[i], 1);
    csr[p] = i;
  }
}

// ---------------- input projection: h = x @ in_w + in_b  (bf16 out) ----------------
__global__ __launch_bounds__(256) void k_inproj(
    const float* __restrict__ x, const float* __restrict__ w,
    const float* __restrict__ b, unsigned short* __restrict__ h, int n)
{
  __shared__ float xs[32 * F_IN];
  const int n0 = blockIdx.x * 32;
  const int tid = threadIdx.x;
  const int maxidx = n * F_IN;
  for (int idx = tid; idx < 32 * F_IN; idx += 256){
    int gidx = n0 * F_IN + idx;
    xs[idx] = (gidx < maxidx) ? x[gidx] : 0.f;
  }
  __syncthreads();
  float acc[32];
  #pragma unroll
  for (int i = 0; i < 32; ++i) acc[i] = 0.f;
  for (int k = 0; k < F_IN; ++k){
    float wk = w[k * HDIM + tid];
    #pragma unroll
    for (int i = 0; i < 32; ++i) acc[i] += xs[i * F_IN + k] * wk;
  }
  float bb = b[tid];
  #pragma unroll
  for (int i = 0; i < 32; ++i){
    int r = n0 + i;
    if (r < n) h[(size_t)r * HDIM + tid] = f2bf(acc[i] + bb);
  }
}

// ---------------- GEMM: C[M,256] = A[M,256](bf16) @ W[256,256](f32) + bias, bf16 out
// 64x128 tile, 256 threads, each thread 4x8
__global__ __launch_bounds__(256) void k_gemm(
    const unsigned short* __restrict__ A, const float* __restrict__ W,
    const float* __restrict__ bias, unsigned short* __restrict__ C, int M)
{
  __shared__ float As[16][64];
  __shared__ float Bs[16][128];
  const int tid = threadIdx.x;
  const int tx = tid & 15;
  const int ty = tid >> 4;
  const int row0 = blockIdx.x * 64;
  const int col0 = blockIdx.y * 128;
  float acc[4][8];
  #pragma unroll
  for (int i = 0; i < 4; ++i)
    #pragma unroll
    for (int j = 0; j < 8; ++j) acc[i][j] = 0.f;

  const int la_row = tid >> 2;          // 0..63
  const int la_k   = (tid & 3) << 2;    // 0,4,8,12
  int arow = row0 + la_row; if (arow > M - 1) arow = M - 1;
  const unsigned short* Ap = A + (size_t)arow * HDIM + la_k;
  const int lb_k = tid >> 4;            // 0..15
  const int lb_c = (tid & 15) << 3;     // 0..120
  const float* Wp = W + lb_k * HDIM + col0 + lb_c;

  for (int k0 = 0; k0 < HDIM; k0 += 16){
    ushort4 a4 = *(const ushort4*)(Ap + k0);
    float4 b0 = *(const float4*)(Wp + k0 * HDIM);
    float4 b1 = *(const float4*)(Wp + k0 * HDIM + 4);
    As[la_k + 0][la_row] = bf2f(a4.x);
    As[la_k + 1][la_row] = bf2f(a4.y);
    As[la_k + 2][la_row] = bf2f(a4.z);
    As[la_k + 3][la_row] = bf2f(a4.w);
    *(float4*)&Bs[lb_k][lb_c]     = b0;
    *(float4*)&Bs[lb_k][lb_c + 4] = b1;
    __syncthreads();
    #pragma unroll
    for (int k = 0; k < 16; ++k){
      float4 av  = *(const float4*)&As[k][ty << 2];
      float4 bv0 = *(const float4*)&Bs[k][tx << 2];
      float4 bv1 = *(const float4*)&Bs[k][(tx << 2) + 64];
      float a_[4] = {av.x, av.y, av.z, av.w};
      float b_[8] = {bv0.x, bv0.y, bv0.z, bv0.w, bv1.x, bv1.y, bv1.z, bv1.w};
      #pragma unroll
      for (int i = 0; i < 4; ++i)
        #pragma unroll
        for (int j = 0; j < 8; ++j)
          acc[i][j] = fmaf(a_[i], b_[j], acc[i][j]);
    }
    __syncthreads();
  }
  #pragma unroll
  for (int i = 0; i < 4; ++i){
    int r = row0 + (ty << 2) + i;
    if (r >= M) continue;
    #pragma unroll
    for (int half = 0; half < 2; ++half){
      int c = col0 + (tx << 2) + half * 64;
      ushort4 st;
      st.x = f2bf(acc[i][half * 4 + 0] + bias[c + 0]);
      st.y = f2bf(acc[i][half * 4 + 1] + bias[c + 1]);
      st.z = f2bf(acc[i][half * 4 + 2] + bias[c + 2]);
      st.w = f2bf(acc[i][half * 4 + 3] + bias[c + 3]);
      *(ushort4*)(C + (size_t)r * HDIM + c) = st;
    }
  }
}

// ---------------- fused GATv2 layer: online softmax + bias + residual + LN + relu
// one wave per dst node; lane owns elems [4*lane, 4*lane+4); head = lane>>3
__global__ __launch_bounds__(256) void k_gat(
    const unsigned short* __restrict__ xl, const unsigned short* __restrict__ xr,
    const int* __restrict__ rp, const int* __restrict__ csr,
    const float* __restrict__ att, const float* __restrict__ gb,
    const float* __restrict__ lg, const float* __restrict__ lb,
    const unsigned short* __restrict__ hold, unsigned short* __restrict__ hnew,
    int n, int use_res)
{
  const int node = blockIdx.x * 4 + (threadIdx.x >> 6);
  if (node >= n) return;
  const int lane = threadIdx.x & 63;
  const int elem = lane << 2;
  const int head = lane >> 3;
  float4 attv = *(const float4*)(att + head * HEADD + (elem & 31));
  ushort4 ur = *(const ushort4*)(xr + (size_t)node * HDIM + elem);
  const float xr0 = bf2f(ur.x), xr1 = bf2f(ur.y), xr2 = bf2f(ur.z), xr3 = bf2f(ur.w);
  float m = -1e30f, l = 0.f, a0 = 0.f, a1 = 0.f, a2 = 0.f, a3 = 0.f;
  const int e0 = rp[node], e1 = rp[node + 1];
  for (int e = e0; e < e1; ++e){
    int s = csr[e];
    ushort4 u = *(const ushort4*)(xl + (size_t)s * HDIM + elem);
    float x0 = bf2f(u.x), x1 = bf2f(u.y), x2 = bf2f(u.z), x3 = bf2f(u.w);
    float t0 = x0 + xr0; t0 = t0 > 0.f ? t0 : SLOPE * t0;
    float t1 = x1 + xr1; t1 = t1 > 0.f ? t1 : SLOPE * t1;
    float t2 = x2 + xr2; t2 = t2 > 0.f ? t2 : SLOPE * t2;
    float t3 = x3 + xr3; t3 = t3 > 0.f ? t3 : SLOPE * t3;
    float p = attv.x * t0 + attv.y * t1 + attv.z * t2 + attv.w * t3;
    p += __shfl_xor(p, 1);
    p += __shfl_xor(p, 2);
    p += __shfl_xor(p, 4);          // per-head score, shared by 8-lane group
    float mn = fmaxf(m, p);
    float sc = __expf(m - mn);
    float pe = __expf(p - mn);
    l  = l  * sc + pe;
    a0 = a0 * sc + pe * x0;
    a1 = a1 * sc + pe * x1;
    a2 = a2 * sc + pe * x2;
    a3 = a3 * sc + pe * x3;
    m = mn;
  }
  const float inv = 1.f / l;
  const size_t base = (size_t)node * HDIM + elem;
  float f0 = a0 * inv + gb[elem + 0];
  float f1 = a1 * inv + gb[elem + 1];
  float f2 = a2 * inv + gb[elem + 2];
  float f3 = a3 * inv + gb[elem + 3];
  if (use_res){
    ushort4 hv = *(const ushort4*)(hold + base);
    f0 += bf2f(hv.x); f1 += bf2f(hv.y); f2 += bf2f(hv.z); f3 += bf2f(hv.w);
  }
  float s = f0 + f1 + f2 + f3;
  #pragma unroll
  for (int off = 1; off < 64; off <<= 1) s += __shfl_xor(s, off);
  const float mean = s * (1.f / HDIM);
  float d0 = f0 - mean, d1 = f1 - mean, d2 = f2 - mean, d3 = f3 - mean;
  float q = d0 * d0 + d1 * d1 + d2 * d2 + d3 * d3;
  #pragma unroll
  for (int off = 1; off < 64; off <<= 1) q += __shfl_xor(q, off);
  const float rs = rsqrtf(q * (1.f / HDIM) + EPSN);
  float o0 = d0 * rs * lg[elem + 0] + lb[elem + 0]; o0 = o0 > 0.f ? o0 : 0.f;
  float o1 = d1 * rs * lg[elem + 1] + lb[elem + 1]; o1 = o1 > 0.f ? o1 : 0.f;
  float o2 = d2 * rs * lg[elem + 2] + lb[elem + 2]; o2 = o2 > 0.f ? o2 : 0.f;
  float o3 = d3 * rs * lg[elem + 3] + lb[elem + 3]; o3 = o3 > 0.f ? o3 : 0.f;
  ushort4 st; st.x = f2bf(o0); st.y = f2bf(o1); st.z = f2bf(o2); st.w = f2bf(o3);
  *(ushort4*)(hnew + base) = st;
}

// ---------------- mean pool over graphs ----------------
__global__ __launch_bounds__(256) void k_pool(
    const unsigned short* __restrict__ ho, const int* __restrict__ batch,
    float* __restrict__ gr, float* __restrict__ cnt, int n)
{
  int node = blockIdx.x * 4 + (threadIdx.x >> 6);
  if (node >= n) return;
  int lane = threadIdx.x & 63;
  int g = batch[node];
  ushort4 v = *(const ushort4*)(ho + (size_t)node * HDIM + (lane << 2));
  float* dst = gr + (size_t)g * HDIM + (lane << 2);
  atomicAdd(dst + 0, bf2f(v.x));
  atomicAdd(dst + 1, bf2f(v.y));
  atomicAdd(dst + 2, bf2f(v.z));
  atomicAdd(dst + 3, bf2f(v.w));
  if (lane == 0) atomicAdd(cnt + g, 1.0f);
}
__global__ void k_poolmean(float* __restrict__ gr, const float* __restrict__ cnt, int g_){
  int g = blockIdx.x, j = threadIdx.x;
  float c = cnt[g]; c = c < 1.f ? 1.f : c;
  gr[(size_t)g * HDIM + j] /= c;
}

// ---------------- tiny MLP ----------------
__global__ void k_fc(const float* __restrict__ in, const float* __restrict__ w,
                     const float* __restrict__ b, float* __restrict__ out,
                     int kin, int kout){
  __shared__ float s[256];
  int g = blockIdx.x, j = threadIdx.x;
  for (int k = j; k < kin; k += blockDim.x) s[k] = in[(size_t)g * kin + k];
  __syncthreads();
  float a = b[j];
  for (int k = 0; k < kin; ++k) a = fmaf(s[k], w[k * kout + j], a);
  out[(size_t)g * kout + j] = a;
}
__global__ __launch_bounds__(256) void k_bnstats(const float* __restrict__ z,
    float* __restrict__ mean, float* __restrict__ rstd, int g_, int c_){
  int c = blockIdx.x;
  float s = 0.f, s2 = 0.f;
  for (int r = threadIdx.x; r < g_; r += 256){
    float v = z[(size_t)r * c_ + c];
    s += v; s2 += v * v;
  }
  #pragma unroll
  for (int off = 1; off < 64; off <<= 1){ s += __shfl_xor(s, off); s2 += __shfl_xor(s2, off); }
  __shared__ float sw[4], sw2[4];
  int lane = threadIdx.x & 63, wid = threadIdx.x >> 6;
  if (lane == 0){ sw[wid] = s; sw2[wid] = s2; }
  __syncthreads();
  if (threadIdx.x == 0){
    float ts = sw[0] + sw[1] + sw[2] + sw[3];
    float ts2 = sw2[0] + sw2[1] + sw2[2] + sw2[3];
    float mm = ts / g_;
    float vv = ts2 / g_ - mm * mm;
    mean[c] = mm; rstd[c] = rsqrtf(vv + EPSN);
  }
}
__global__ void k_bnrelu(float* __restrict__ z, const float* __restrict__ mean,
                         const float* __restrict__ rstd, const float* __restrict__ g,
                         const float* __restrict__ b, int total, int c_){
  int i = blockIdx.x * 256 + threadIdx.x;
  if (i < total){
    int c = i & (c_ - 1);
    float v = (z[i] - mean[c]) * rstd[c] * g[c] + b[c];
    z[i] = v > 0.f ? v : 0.f;
  }
}
__global__ __launch_bounds__(256) void k_out(const float* __restrict__ z,
    const float* __restrict__ w, const float* __restrict__ b,
    float* __restrict__ out, int g_){
  int g = blockIdx.x * 4 + (threadIdx.x >> 6);
  if (g >= g_) return;
  int lane = threadIdx.x & 63;
  float v = z[(size_t)g * 64 + lane] * w[lane];
  #pragma unroll
  for (int off = 1; off < 64; off <<= 1) v += __shfl_xor(v, off);
  if (lane == 0) out[g] = v + b[0];
}

// ---------------- host ----------------
extern "C" void kernel_launch(void* const* d_in, const int* in_sizes, int n_in,
                              void* d_out, int out_size, void* d_ws, size_t ws_size,
                              hipStream_t stream)
{
  const float* x     = (const float*)d_in[0];
  const int*   ei    = (const int*)  d_in[1];
  const int*   batch = (const int*)  d_in[2];
  const float* in_w  = (const float*)d_in[3];
  const float* in_b  = (const float*)d_in[4];
  const float* wl    = (const float*)d_in[5];
  const float* wl_b  = (const float*)d_in[6];
  const float* wr    = (const float*)d_in[7];
  const float* wr_b  = (const float*)d_in[8];
  const float* att   = (const float*)d_in[9];
  const float* gat_b = (const float*)d_in[10];
  const float* ln_g  = (const float*)d_in[11];
  const float* ln_b  = (const float*)d_in[12];
  const float* out_w = (const float*)d_in[13];
  const float* out_b = (const float*)d_in[14];
  const float* p1_w  = (const float*)d_in[15];
  const float* p1_b  = (const float*)d_in[16];
  const float* bn1_g = (const float*)d_in[17];
  const float* bn1_b = (const float*)d_in[18];
  const float* p2_w  = (const float*)d_in[19];
  const float* p2_b  = (const float*)d_in[20];
  const float* bn2_g = (const float*)d_in[21];
  const float* bn2_b = (const float*)d_in[22];
  const float* p3_w  = (const float*)d_in[23];
  const float* p3_b  = (const float*)d_in[24];

  const int n = in_sizes[0] / F_IN;     // 50000
  const int e = in_sizes[1] / 2;        // 800000
  const int g = out_size;               // 500 graphs (OUT=1)

  char* p = (char*)d_ws;
  auto take = [&](size_t bytes)->char*{
    char* q = p; p += ((bytes + 255) & ~(size_t)255); return q;
  };
  unsigned short* hA  = (unsigned short*)take((size_t)n * HDIM * 2);
  unsigned short* hB  = (unsigned short*)take((size_t)n * HDIM * 2);
  unsigned short* xlb = (unsigned short*)take((size_t)n * HDIM * 2);
  unsigned short* xrb = (unsigned short*)take((size_t)n * HDIM * 2);
  int*   deg   = (int*)take((size_t)n * 4);
  int*   rowp  = (int*)take((size_t)(n + 1) * 4);
  int*   cur   = (int*)take((size_t)n * 4);
  int*   csr   = (int*)take((size_t)(e + n) * 4);
  float* gr    = (float*)take((size_t)g * HDIM * 4);
  float* cnt   = (float*)take((size_t)g * 4);
  float* z1    = (float*)take((size_t)g * 128 * 4);
  float* z2    = (float*)take((size_t)g * 64 * 4);
  float* mean1 = (float*)take(128 * 4);
  float* rstd1 = (float*)take(128 * 4);
  float* mean2 = (float*)take(64 * 4);
  float* rstd2 = (float*)take(64 * 4);
  (void)ws_size; (void)n_in;

  // CSR build
  hipMemsetAsync(deg, 0, (size_t)n * 4, stream);
  k_hist<<<(e + 255) / 256, 256, 0, stream>>>(ei + e, deg, e);
  k_scan<<<1, 256, 0, stream>>>(deg, rowp, n);
  k_copy<<<(n + 255) / 256, 256, 0, stream>>>(rowp, cur, n);
  k_fill<<<(e + 255) / 256, 256, 0, stream>>>(ei, ei + e, cur, csr, e);
  k_fillself<<<(n + 255) / 256, 256, 0, stream>>>(cur, csr, n);

  // input projection
  k_inproj<<<(n + 31) / 32, 256, 0, stream>>>(x, in_w, in_b, hA, n);

  unsigned short* hcur = hA;
  unsigned short* hnext = hB;
  dim3 gemm_grid((n + 63) / 64, 2);
  for (int i = 0; i < NLAYER; ++i){
    k_gemm<<<gemm_grid, 256, 0, stream>>>(hcur, wl + (size_t)i * HDIM * HDIM,
                                          wl_b + i * HDIM, xlb, n);
    k_gemm<<<gemm_grid, 256, 0, stream>>>(hcur, wr + (size_t)i * HDIM * HDIM,
                                          wr_b + i * HDIM, xrb, n);
    k_gat<<<(n + 3) / 4, 256, 0, stream>>>(xlb, xrb, rowp, csr,
        att + (size_t)i * NHEAD * HEADD, gat_b + i * HDIM,
        ln_g + i * HDIM, ln_b + i * HDIM, hcur, hnext, n, i > 0 ? 1 : 0);
    unsigned short* t = hcur; hcur = hnext; hnext = t;
  }
  // output projection (reuse xlb as ho, bf16)
  k_gemm<<<gemm_grid, 256, 0, stream>>>(hcur, out_w, out_b, xlb, n);

  // pooling
  hipMemsetAsync(gr, 0, (size_t)g * HDIM * 4, stream);
  hipMemsetAsync(cnt, 0, (size_t)g * 4, stream);
  k_pool<<<(n + 3) / 4, 256, 0, stream>>>(xlb, batch, gr, cnt, n);
  k_poolmean<<<g, HDIM, 0, stream>>>(gr, cnt, g);

  // MLP head
  k_fc<<<g, 128, 0, stream>>>(gr, p1_w, p1_b, z1, HDIM, 128);
  k_bnstats<<<128, 256, 0, stream>>>(z1, mean1, rstd1, g, 128);
  k_bnrelu<<<(g * 128 + 255) / 256, 256, 0, stream>>>(z1, mean1, rstd1, bn1_g, bn1_b, g * 128, 128);
  k_fc<<<g, 64, 0, stream>>>(z1, p2_w, p2_b, z2, 128, 64);
  k_bnstats<<<64, 256, 0, stream>>>(z2, mean2, rstd2, g, 64);
  k_bnrelu<<<(g * 64 + 255) / 256, 256, 0, stream>>>(z2, mean2, rstd2, bn2_g, bn2_b, g * 64, 64);
  k_out<<<(g + 3) / 4, 256, 0, stream>>>(z2, p3_w, p3_b, (float*)d_out, g);
}

// Round 2
// 1073.124 us; speedup vs baseline: 1.6447x; 1.6447x over previous
//
#include <hip/hip_runtime.h>
#include <hip/hip_bf16.h>

#define F_IN   74
#define HDIM   256
#define NHEAD  8
#define HEADD  32
#define NLAYER 4
#define SLOPE  0.2f
#define EPSN   1e-5f

typedef __attribute__((ext_vector_type(8))) short bf16x8;
typedef __attribute__((ext_vector_type(4))) float f32x4;

__device__ __forceinline__ float bf2f(unsigned short u){
  union { unsigned int i; float f; } x; x.i = ((unsigned int)u) << 16; return x.f;
}
__device__ __forceinline__ unsigned short f2bf(float f){
  union { float f; unsigned int i; } x; x.f = f;
  unsigned int u = x.i;
  return (unsigned short)((u + 0x7FFFu + ((u >> 16) & 1u)) >> 16);
}

#define GLOAD16(g, s) __builtin_amdgcn_global_load_lds( \
  (const __attribute__((address_space(1))) void*)(g), \
  (__attribute__((address_space(3))) void*)(s), 16, 0, 0)

// ---------------- CSR build (dst-grouped) ----------------
__global__ void k_hist(const int* __restrict__ dst, int* __restrict__ deg, int e){
  int i = blockIdx.x * 256 + threadIdx.x;
  if (i < e) atomicAdd(&deg[dst[i]], 1);
}

__global__ __launch_bounds__(256) void k_scan(const int* __restrict__ deg,
                                              int* __restrict__ rowp, int n){
  __shared__ int wsum[4];
  __shared__ int carry;
  const int tid = threadIdx.x, lane = tid & 63, wid = tid >> 6;
  if (tid == 0) carry = 0;
  __syncthreads();
  for (int base = 0; base < n; base += 256){
    int i = base + tid;
    int v = (i < n) ? (deg[i] + 1) : 0;   // +1 self-loop
    int xv = v;
    #pragma unroll
    for (int off = 1; off < 64; off <<= 1){
      int t = __shfl_up(xv, off);
      if (lane >= off) xv += t;
    }
    if (lane == 63) wsum[wid] = xv;
    __syncthreads();
    int woff = 0, total = 0;
    #pragma unroll
    for (int w = 0; w < 4; ++w){
      int s = wsum[w];
      total += s;
      if (w < wid) woff += s;
    }
    if (i < n) rowp[i] = carry + woff + xv - v;
    __syncthreads();
    if (tid == 0) carry += total;
    __syncthreads();
  }
  if (threadIdx.x == 0) rowp[n] = carry;
}

__global__ void k_copy(const int* __restrict__ a, int* __restrict__ b, int n){
  int i = blockIdx.x * 256 + threadIdx.x;
  if (i < n) b[i] = a[i];
}
__global__ void k_fill(const int* __restrict__ src, const int* __restrict__ dst,
                       int* __restrict__ cur, int* __restrict__ csr, int e){
  int i = blockIdx.x * 256 + threadIdx.x;
  if (i < e){
    int p = atomicAdd(&cur[dst[i]], 1);
    csr[p] = src[i];
  }
}
__global__ void k_fillself(int* __restrict__ cur, int* __restrict__ csr, int n){
  int i = blockIdx.x * 256 + threadIdx.x;
  if (i < n){
    int p = atomicAdd(&cur[i], 1);
    csr[p] = i;
  }
}

// ---------------- input projection: h = x @ in_w + in_b  (bf16 out) ----------------
__global__ __launch_bounds__(256) void k_inproj(
    const float* __restrict__ x, const float* __restrict__ w,
    const float* __restrict__ b, unsigned short* __restrict__ h, int n)
{
  __shared__ float xs[32 * F_IN];
  const int n0 = blockIdx.x * 32;
  const int tid = threadIdx.x;
  const int maxidx = n * F_IN;
  for (int idx = tid; idx < 32 * F_IN; idx += 256){
    int gidx = n0 * F_IN + idx;
    xs[idx] = (gidx < maxidx) ? x[gidx] : 0.f;
  }
  __syncthreads();
  float acc[32];
  #pragma unroll
  for (int i = 0; i < 32; ++i) acc[i] = 0.f;
  for (int k = 0; k < F_IN; ++k){
    float wk = w[k * HDIM + tid];
    #pragma unroll
    for (int i = 0; i < 32; ++i) acc[i] += xs[i * F_IN + k] * wk;
  }
  float bb = b[tid];
  #pragma unroll
  for (int i = 0; i < 32; ++i){
    int r = n0 + i;
    if (r < n) h[(size_t)r * HDIM + tid] = f2bf(acc[i] + bb);
  }
}

// ---------------- weight convert: Wt[mat][n][k] = (bf16)W[mat][k][n] ----------------
__global__ __launch_bounds__(256) void k_wconv(const float* __restrict__ W,
    unsigned short* __restrict__ Wt){
  __shared__ float tile[32][33];
  const int mat = blockIdx.z;
  const float* Wm = W + (size_t)mat * HDIM * HDIM;
  unsigned short* Wo = Wt + (size_t)mat * HDIM * HDIM;
  const int c0 = blockIdx.x * 32, r0 = blockIdx.y * 32;
  const int tx = threadIdx.x & 31, ty = threadIdx.x >> 5;  // 32 x 8
  #pragma unroll
  for (int i = 0; i < 32; i += 8)
    tile[ty + i][tx] = Wm[(size_t)(r0 + ty + i) * HDIM + c0 + tx];
  __syncthreads();
  #pragma unroll
  for (int i = 0; i < 32; i += 8)
    Wo[(size_t)(c0 + ty + i) * HDIM + r0 + tx] = f2bf(tile[tx][ty + i]);
}

// ---------------- MFMA GEMM: C[M,256](bf16) = A[M,256](bf16) @ Wt^T + bias
// Wt is [256 n][256 k] (pre-transposed). 128x128 tile, BK=64, 4 waves (2x2),
// global_load_lds w/ pre-swizzled source, XOR-swizzled ds_read_b128,
// double-buffered LDS, raw barriers + counted vmcnt.
__global__ __launch_bounds__(256) void k_gemm_mfma(
    const unsigned short* __restrict__ A, const unsigned short* __restrict__ Wt,
    const float* __restrict__ bias, unsigned short* __restrict__ C, int M)
{
  __shared__ unsigned short As[2][128 * 64];
  __shared__ unsigned short Bs[2][128 * 64];
  const int tid = threadIdx.x;
  const int l   = tid & 63;
  const int w   = tid >> 6;           // wave 0..3
  const int wm  = w >> 1, wn = w & 1; // 2x2 wave grid, 64x64 per wave
  const int row0 = blockIdx.x * 128;
  const int col0 = blockIdx.y * 128;

  const int srow   = l >> 3;          // 0..7 (row within 8-row group)
  const int schunk = l & 7;           // 16B chunk within 128B row

  f32x4 acc[4][4];
  #pragma unroll
  for (int i = 0; i < 4; ++i)
    #pragma unroll
    for (int j = 0; j < 4; ++j) acc[i][j] = (f32x4){0.f, 0.f, 0.f, 0.f};

  auto stage = [&](int buf, int k0){
    #pragma unroll
    for (int i = 0; i < 4; ++i){
      const int rloc = w * 32 + i * 8 + srow;             // 0..127
      const int sw   = (schunk ^ (rloc & 7)) * 16;        // swizzled 16B chunk (bytes)
      int ra = row0 + rloc; if (ra > M - 1) ra = M - 1;
      const char* srcA = (const char*)(A + (size_t)ra * HDIM + k0) + sw;
      GLOAD16(srcA, &As[buf][(w * 32 + i * 8) * 64]);
      const char* srcB = (const char*)(Wt + (size_t)(col0 + rloc) * HDIM + k0) + sw;
      GLOAD16(srcB, &Bs[buf][(w * 32 + i * 8) * 64]);
    }
  };

  auto compute = [&](int buf){
    #pragma unroll
    for (int kk = 0; kk < 2; ++kk){          // two k=32 slices of the BK=64 tile
      bf16x8 af[4], bfr[4];
      #pragma unroll
      for (int mi = 0; mi < 4; ++mi){
        const int row = wm * 64 + mi * 16 + (l & 15);
        const int t   = (kk * 4 + (l >> 4)) ^ (row & 7);
        af[mi] = *(const bf16x8*)((const char*)&As[buf][0] + row * 128 + t * 16);
      }
      #pragma unroll
      for (int ni = 0; ni < 4; ++ni){
        const int nn = wn * 64 + ni * 16 + (l & 15);
        const int t  = (kk * 4 + (l >> 4)) ^ (nn & 7);
        bfr[ni] = *(const bf16x8*)((const char*)&Bs[buf][0] + nn * 128 + t * 16);
      }
      #pragma unroll
      for (int mi = 0; mi < 4; ++mi)
        #pragma unroll
        for (int ni = 0; ni < 4; ++ni)
          acc[mi][ni] = __builtin_amdgcn_mfma_f32_16x16x32_bf16(
              af[mi], bfr[ni], acc[mi][ni], 0, 0, 0);
    }
  };

  stage(0, 0);
  int cur = 0;
  #pragma unroll
  for (int t = 0; t < 4; ++t){
    if (t < 3){
      stage(cur ^ 1, (t + 1) * 64);
      asm volatile("s_waitcnt vmcnt(8)" ::: "memory");
    } else {
      asm volatile("s_waitcnt vmcnt(0)" ::: "memory");
    }
    __builtin_amdgcn_s_barrier();
    compute(cur);
    asm volatile("" ::: "memory");
    __builtin_amdgcn_s_barrier();
    cur ^= 1;
  }

  #pragma unroll
  for (int mi = 0; mi < 4; ++mi){
    #pragma unroll
    for (int ni = 0; ni < 4; ++ni){
      const int col = col0 + wn * 64 + ni * 16 + (l & 15);
      const float bv = bias[col];
      #pragma unroll
      for (int r = 0; r < 4; ++r){
        const int row = row0 + wm * 64 + mi * 16 + (l >> 4) * 4 + r;
        if (row < M) C[(size_t)row * HDIM + col] = f2bf(acc[mi][ni][r] + bv);
      }
    }
  }
}

// ---------------- fused GATv2 layer: online softmax + bias + residual + LN + relu
__global__ __launch_bounds__(256) void k_gat(
    const unsigned short* __restrict__ xl, const unsigned short* __restrict__ xr,
    const int* __restrict__ rp, const int* __restrict__ csr,
    const float* __restrict__ att, const float* __restrict__ gb,
    const float* __restrict__ lg, const float* __restrict__ lb,
    const unsigned short* __restrict__ hold, unsigned short* __restrict__ hnew,
    int n, int use_res)
{
  const int node = blockIdx.x * 4 + (threadIdx.x >> 6);
  if (node >= n) return;
  const int lane = threadIdx.x & 63;
  const int elem = lane << 2;
  const int head = lane >> 3;
  float4 attv = *(const float4*)(att + head * HEADD + (elem & 31));
  ushort4 ur = *(const ushort4*)(xr + (size_t)node * HDIM + elem);
  const float xr0 = bf2f(ur.x), xr1 = bf2f(ur.y), xr2 = bf2f(ur.z), xr3 = bf2f(ur.w);
  float m = -1e30f, l = 0.f, a0 = 0.f, a1 = 0.f, a2 = 0.f, a3 = 0.f;
  const int e0 = rp[node], e1 = rp[node + 1];
  for (int e = e0; e < e1; ++e){
    int s = csr[e];
    ushort4 u = *(const ushort4*)(xl + (size_t)s * HDIM + elem);
    float x0 = bf2f(u.x), x1 = bf2f(u.y), x2 = bf2f(u.z), x3 = bf2f(u.w);
    float t0 = x0 + xr0; t0 = t0 > 0.f ? t0 : SLOPE * t0;
    float t1 = x1 + xr1; t1 = t1 > 0.f ? t1 : SLOPE * t1;
    float t2 = x2 + xr2; t2 = t2 > 0.f ? t2 : SLOPE * t2;
    float t3 = x3 + xr3; t3 = t3 > 0.f ? t3 : SLOPE * t3;
    float p = attv.x * t0 + attv.y * t1 + attv.z * t2 + attv.w * t3;
    p += __shfl_xor(p, 1);
    p += __shfl_xor(p, 2);
    p += __shfl_xor(p, 4);          // per-head score, shared by 8-lane group
    float mn = fmaxf(m, p);
    float sc = __expf(m - mn);
    float pe = __expf(p - mn);
    l  = l  * sc + pe;
    a0 = a0 * sc + pe * x0;
    a1 = a1 * sc + pe * x1;
    a2 = a2 * sc + pe * x2;
    a3 = a3 * sc + pe * x3;
    m = mn;
  }
  const float inv = 1.f / l;
  const size_t base = (size_t)node * HDIM + elem;
  float f0 = a0 * inv + gb[elem + 0];
  float f1 = a1 * inv + gb[elem + 1];
  float f2 = a2 * inv + gb[elem + 2];
  float f3 = a3 * inv + gb[elem + 3];
  if (use_res){
    ushort4 hv = *(const ushort4*)(hold + base);
    f0 += bf2f(hv.x); f1 += bf2f(hv.y); f2 += bf2f(hv.z); f3 += bf2f(hv.w);
  }
  float s = f0 + f1 + f2 + f3;
  #pragma unroll
  for (int off = 1; off < 64; off <<= 1) s += __shfl_xor(s, off);
  const float mean = s * (1.f / HDIM);
  float d0 = f0 - mean, d1 = f1 - mean, d2 = f2 - mean, d3 = f3 - mean;
  float q = d0 * d0 + d1 * d1 + d2 * d2 + d3 * d3;
  #pragma unroll
  for (int off = 1; off < 64; off <<= 1) q += __shfl_xor(q, off);
  const float rs = rsqrtf(q * (1.f / HDIM) + EPSN);
  float o0 = d0 * rs * lg[elem + 0] + lb[elem + 0]; o0 = o0 > 0.f ? o0 : 0.f;
  float o1 = d1 * rs * lg[elem + 1] + lb[elem + 1]; o1 = o1 > 0.f ? o1 : 0.f;
  float o2 = d2 * rs * lg[elem + 2] + lb[elem + 2]; o2 = o2 > 0.f ? o2 : 0.f;
  float o3 = d3 * rs * lg[elem + 3] + lb[elem + 3]; o3 = o3 > 0.f ? o3 : 0.f;
  ushort4 st; st.x = f2bf(o0); st.y = f2bf(o1); st.z = f2bf(o2); st.w = f2bf(o3);
  *(ushort4*)(hnew + base) = st;
}

// ---------------- mean pool: batch is sorted -> per-graph segment reduce ----------------
__global__ __launch_bounds__(256) void k_pool2(
    const unsigned short* __restrict__ ho, const int* __restrict__ batch,
    float* __restrict__ gr, int n)
{
  const int g = blockIdx.x;
  int lo = 0, hi = n;
  while (lo < hi){ int mid = (lo + hi) >> 1; if (batch[mid] < g) lo = mid + 1; else hi = mid; }
  const int s = lo;
  hi = n;
  while (lo < hi){ int mid = (lo + hi) >> 1; if (batch[mid] < g + 1) lo = mid + 1; else hi = mid; }
  const int e = lo;
  const int j = threadIdx.x;
  float acc = 0.f;
  for (int i = s; i < e; ++i) acc += bf2f(ho[(size_t)i * HDIM + j]);
  int c = e - s; if (c < 1) c = 1;
  gr[(size_t)g * HDIM + j] = acc / (float)c;
}

// ---------------- tiny MLP ----------------
__global__ void k_fc(const float* __restrict__ in, const float* __restrict__ w,
                     const float* __restrict__ b, float* __restrict__ out,
                     int kin, int kout){
  __shared__ float s[256];
  int g = blockIdx.x, j = threadIdx.x;
  for (int k = j; k < kin; k += blockDim.x) s[k] = in[(size_t)g * kin + k];
  __syncthreads();
  float a = b[j];
  for (int k = 0; k < kin; ++k) a = fmaf(s[k], w[k * kout + j], a);
  out[(size_t)g * kout + j] = a;
}
__global__ __launch_bounds__(256) void k_bnstats(const float* __restrict__ z,
    float* __restrict__ mean, float* __restrict__ rstd, int g_, int c_){
  int c = blockIdx.x;
  float s = 0.f, s2 = 0.f;
  for (int r = threadIdx.x; r < g_; r += 256){
    float v = z[(size_t)r * c_ + c];
    s += v; s2 += v * v;
  }
  #pragma unroll
  for (int off = 1; off < 64; off <<= 1){ s += __shfl_xor(s, off); s2 += __shfl_xor(s2, off); }
  __shared__ float sw[4], sw2[4];
  int lane = threadIdx.x & 63, wid = threadIdx.x >> 6;
  if (lane == 0){ sw[wid] = s; sw2[wid] = s2; }
  __syncthreads();
  if (threadIdx.x == 0){
    float ts = sw[0] + sw[1] + sw[2] + sw[3];
    float ts2 = sw2[0] + sw2[1] + sw2[2] + sw2[3];
    float mm = ts / g_;
    float vv = ts2 / g_ - mm * mm;
    mean[c] = mm; rstd[c] = rsqrtf(vv + EPSN);
  }
}
__global__ void k_bnrelu(float* __restrict__ z, const float* __restrict__ mean,
                         const float* __restrict__ rstd, const float* __restrict__ g,
                         const float* __restrict__ b, int total, int c_){
  int i = blockIdx.x * 256 + threadIdx.x;
  if (i < total){
    int c = i & (c_ - 1);
    float v = (z[i] - mean[c]) * rstd[c] * g[c] + b[c];
    z[i] = v > 0.f ? v : 0.f;
  }
}
__global__ __launch_bounds__(256) void k_out(const float* __restrict__ z,
    const float* __restrict__ w, const float* __restrict__ b,
    float* __restrict__ out, int g_){
  int g = blockIdx.x * 4 + (threadIdx.x >> 6);
  if (g >= g_) return;
  int lane = threadIdx.x & 63;
  float v = z[(size_t)g * 64 + lane] * w[lane];
  #pragma unroll
  for (int off = 1; off < 64; off <<= 1) v += __shfl_xor(v, off);
  if (lane == 0) out[g] = v + b[0];
}

// ---------------- host ----------------
extern "C" void kernel_launch(void* const* d_in, const int* in_sizes, int n_in,
                              void* d_out, int out_size, void* d_ws, size_t ws_size,
                              hipStream_t stream)
{
  const float* x     = (const float*)d_in[0];
  const int*   ei    = (const int*)  d_in[1];
  const int*   batch = (const int*)  d_in[2];
  const float* in_w  = (const float*)d_in[3];
  const float* in_b  = (const float*)d_in[4];
  const float* wl    = (const float*)d_in[5];
  const float* wl_b  = (const float*)d_in[6];
  const float* wr    = (const float*)d_in[7];
  const float* wr_b  = (const float*)d_in[8];
  const float* att   = (const float*)d_in[9];
  const float* gat_b = (const float*)d_in[10];
  const float* ln_g  = (const float*)d_in[11];
  const float* ln_b  = (const float*)d_in[12];
  const float* out_w = (const float*)d_in[13];
  const float* out_b = (const float*)d_in[14];
  const float* p1_w  = (const float*)d_in[15];
  const float* p1_b  = (const float*)d_in[16];
  const float* bn1_g = (const float*)d_in[17];
  const float* bn1_b = (const float*)d_in[18];
  const float* p2_w  = (const float*)d_in[19];
  const float* p2_b  = (const float*)d_in[20];
  const float* bn2_g = (const float*)d_in[21];
  const float* bn2_b = (const float*)d_in[22];
  const float* p3_w  = (const float*)d_in[23];
  const float* p3_b  = (const float*)d_in[24];

  const int n = in_sizes[0] / F_IN;     // 50000
  const int e = in_sizes[1] / 2;        // 800000
  const int g = out_size;               // 500

  char* p = (char*)d_ws;
  auto take = [&](size_t bytes)->char*{
    char* q = p; p += ((bytes + 255) & ~(size_t)255); return q;
  };
  unsigned short* hA  = (unsigned short*)take((size_t)n * HDIM * 2);
  unsigned short* hB  = (unsigned short*)take((size_t)n * HDIM * 2);
  unsigned short* xlb = (unsigned short*)take((size_t)n * HDIM * 2);
  unsigned short* xrb = (unsigned short*)take((size_t)n * HDIM * 2);
  unsigned short* WtL = (unsigned short*)take((size_t)4 * HDIM * HDIM * 2);
  unsigned short* WtR = (unsigned short*)take((size_t)4 * HDIM * HDIM * 2);
  unsigned short* WtO = (unsigned short*)take((size_t)1 * HDIM * HDIM * 2);
  int*   deg   = (int*)take((size_t)n * 4);
  int*   rowp  = (int*)take((size_t)(n + 1) * 4);
  int*   cur   = (int*)take((size_t)n * 4);
  int*   csr   = (int*)take((size_t)(e + n) * 4);
  float* gr    = (float*)take((size_t)g * HDIM * 4);
  float* z1    = (float*)take((size_t)g * 128 * 4);
  float* z2    = (float*)take((size_t)g * 64 * 4);
  float* mean1 = (float*)take(128 * 4);
  float* rstd1 = (float*)take(128 * 4);
  float* mean2 = (float*)take(64 * 4);
  float* rstd2 = (float*)take(64 * 4);
  (void)ws_size; (void)n_in;

  // CSR build
  hipMemsetAsync(deg, 0, (size_t)n * 4, stream);
  k_hist<<<(e + 255) / 256, 256, 0, stream>>>(ei + e, deg, e);
  k_scan<<<1, 256, 0, stream>>>(deg, rowp, n);
  k_copy<<<(n + 255) / 256, 256, 0, stream>>>(rowp, cur, n);
  k_fill<<<(e + 255) / 256, 256, 0, stream>>>(ei, ei + e, cur, csr, e);
  k_fillself<<<(n + 255) / 256, 256, 0, stream>>>(cur, csr, n);

  // weight conversion (transpose + bf16)
  k_wconv<<<dim3(8, 8, 4), 256, 0, stream>>>(wl, WtL);
  k_wconv<<<dim3(8, 8, 4), 256, 0, stream>>>(wr, WtR);
  k_wconv<<<dim3(8, 8, 1), 256, 0, stream>>>(out_w, WtO);

  // input projection
  k_inproj<<<(n + 31) / 32, 256, 0, stream>>>(x, in_w, in_b, hA, n);

  unsigned short* hcur = hA;
  unsigned short* hnext = hB;
  dim3 gemm_grid((n + 127) / 128, 2);
  for (int i = 0; i < NLAYER; ++i){
    k_gemm_mfma<<<gemm_grid, 256, 0, stream>>>(hcur, WtL + (size_t)i * HDIM * HDIM,
                                               wl_b + i * HDIM, xlb, n);
    k_gemm_mfma<<<gemm_grid, 256, 0, stream>>>(hcur, WtR + (size_t)i * HDIM * HDIM,
                                               wr_b + i * HDIM, xrb, n);
    k_gat<<<(n + 3) / 4, 256, 0, stream>>>(xlb, xrb, rowp, csr,
        att + (size_t)i * NHEAD * HEADD, gat_b + i * HDIM,
        ln_g + i * HDIM, ln_b + i * HDIM, hcur, hnext, n, i > 0 ? 1 : 0);
    unsigned short* t = hcur; hcur = hnext; hnext = t;
  }
  // output projection (reuse xlb as ho)
  k_gemm_mfma<<<gemm_grid, 256, 0, stream>>>(hcur, WtO, out_b, xlb, n);

  // pooling (batch sorted -> segment reduce, no atomics)
  k_pool2<<<g, 256, 0, stream>>>(xlb, batch, gr, n);

  // MLP head
  k_fc<<<g, 128, 0, stream>>>(gr, p1_w, p1_b, z1, HDIM, 128);
  k_bnstats<<<128, 256, 0, stream>>>(z1, mean1, rstd1, g, 128);
  k_bnrelu<<<(g * 128 + 255) / 256, 256, 0, stream>>>(z1, mean1, rstd1, bn1_g, bn1_b, g * 128, 128);
  k_fc<<<g, 64, 0, stream>>>(z1, p2_w, p2_b, z2, 128, 64);
  k_bnstats<<<64, 256, 0, stream>>>(z2, mean2, rstd2, g, 64);
  k_bnrelu<<<(g * 64 + 255) / 256, 256, 0, stream>>>(z2, mean2, rstd2, bn2_g, bn2_b, g * 64, 64);
  k_out<<<(g + 3) / 4, 256, 0, stream>>>(z2, p3_w, p3_b, (float*)d_out, g);
}

// Round 3
// 758.035 us; speedup vs baseline: 2.3284x; 1.4157x over previous
//
#include <hip/hip_runtime.h>
#include <hip/hip_bf16.h>

#define F_IN   74
#define HDIM   256
#define NHEAD  8
#define HEADD  32
#define NLAYER 4
#define SLOPE  0.2f
#define EPSN   1e-5f

typedef __attribute__((ext_vector_type(8))) short bf16x8;
typedef __attribute__((ext_vector_type(4))) float f32x4;

__device__ __forceinline__ float bf2f(unsigned short u){
  union { unsigned int i; float f; } x; x.i = ((unsigned int)u) << 16; return x.f;
}
__device__ __forceinline__ unsigned short f2bf(float f){
  union { float f; unsigned int i; } x; x.f = f;
  unsigned int u = x.i;
  return (unsigned short)((u + 0x7FFFu + ((u >> 16) & 1u)) >> 16);
}

#define GLOAD16(g, s) __builtin_amdgcn_global_load_lds( \
  (const __attribute__((address_space(1))) void*)(g), \
  (__attribute__((address_space(3))) void*)(s), 16, 0, 0)

// ---------------- CSR build (dst-grouped) ----------------
__global__ void k_hist(const int* __restrict__ dst, int* __restrict__ deg, int e){
  int i = blockIdx.x * 256 + threadIdx.x;
  if (i < e) atomicAdd(&deg[dst[i]], 1);
}

// hierarchical scan of (deg[i]+1): per-block scan + block sums
__global__ __launch_bounds__(256) void k_scan1(const int* __restrict__ deg,
    int* __restrict__ rowp, int* __restrict__ bsum, int n){
  __shared__ int wsum[4];
  const int tid = threadIdx.x, lane = tid & 63, wid = tid >> 6;
  const int i = blockIdx.x * 256 + tid;
  int v = (i < n) ? (deg[i] + 1) : 0;   // +1 self-loop
  int xv = v;
  #pragma unroll
  for (int off = 1; off < 64; off <<= 1){
    int t = __shfl_up(xv, off);
    if (lane >= off) xv += t;
  }
  if (lane == 63) wsum[wid] = xv;
  __syncthreads();
  int woff = 0, total = 0;
  #pragma unroll
  for (int w = 0; w < 4; ++w){
    int s = wsum[w];
    total += s;
    if (w < wid) woff += s;
  }
  if (i < n) rowp[i] = woff + xv - v;    // local exclusive
  if (tid == 0) bsum[blockIdx.x] = total;
}
__global__ __launch_bounds__(256) void k_scan2(const int* __restrict__ bsum,
    int* __restrict__ boff, int nb){
  __shared__ int wsum[4];
  const int tid = threadIdx.x, lane = tid & 63, wid = tid >> 6;
  int v = (tid < nb) ? bsum[tid] : 0;
  int xv = v;
  #pragma unroll
  for (int off = 1; off < 64; off <<= 1){
    int t = __shfl_up(xv, off);
    if (lane >= off) xv += t;
  }
  if (lane == 63) wsum[wid] = xv;
  __syncthreads();
  int woff = 0, total = 0;
  #pragma unroll
  for (int w = 0; w < 4; ++w){
    int s = wsum[w];
    total += s;
    if (w < wid) woff += s;
  }
  if (tid <= nb) boff[tid] = woff + xv - v;   // exclusive; boff[nb] filled below
  if (tid == 0) boff[nb] = total;             // total at end (nb < 256 assumed)
}
__global__ void k_scan3(int* __restrict__ rowp, const int* __restrict__ boff,
                        int n, int nb){
  int i = blockIdx.x * 256 + threadIdx.x;
  if (i < n) rowp[i] += boff[blockIdx.x];
  if (i == 0) rowp[n] = boff[nb];
}

__global__ void k_copy(const int* __restrict__ a, int* __restrict__ b, int n){
  int i = blockIdx.x * 256 + threadIdx.x;
  if (i < n) b[i] = a[i];
}
__global__ void k_fill(const int* __restrict__ src, const int* __restrict__ dst,
                       int* __restrict__ cur, int* __restrict__ csr, int e){
  int i = blockIdx.x * 256 + threadIdx.x;
  if (i < e){
    int p = atomicAdd(&cur[dst[i]], 1);
    csr[p] = src[i];
  }
}
__global__ void k_fillself(int* __restrict__ cur, int* __restrict__ csr, int n){
  int i = blockIdx.x * 256 + threadIdx.x;
  if (i < n){
    int p = atomicAdd(&cur[i], 1);
    csr[p] = i;
  }
}

// ---------------- input projection: h = x @ in_w + in_b  (bf16 out) ----------------
__global__ __launch_bounds__(256) void k_inproj(
    const float* __restrict__ x, const float* __restrict__ w,
    const float* __restrict__ b, unsigned short* __restrict__ h, int n)
{
  __shared__ float xs[32 * F_IN];
  const int n0 = blockIdx.x * 32;
  const int tid = threadIdx.x;
  const int maxidx = n * F_IN;
  for (int idx = tid; idx < 32 * F_IN; idx += 256){
    int gidx = n0 * F_IN + idx;
    xs[idx] = (gidx < maxidx) ? x[gidx] : 0.f;
  }
  __syncthreads();
  float acc[32];
  #pragma unroll
  for (int i = 0; i < 32; ++i) acc[i] = 0.f;
  for (int k = 0; k < F_IN; ++k){
    float wk = w[k * HDIM + tid];
    #pragma unroll
    for (int i = 0; i < 32; ++i) acc[i] += xs[i * F_IN + k] * wk;
  }
  float bb = b[tid];
  #pragma unroll
  for (int i = 0; i < 32; ++i){
    int r = n0 + i;
    if (r < n) h[(size_t)r * HDIM + tid] = f2bf(acc[i] + bb);
  }
}

// ---------------- weight convert: Wt[n][k] = (bf16)W[k][n], strided output ----------------
__global__ __launch_bounds__(256) void k_wconv(const float* __restrict__ W,
    unsigned short* __restrict__ Wt, size_t mat_stride){
  __shared__ float tile[32][33];
  const int mat = blockIdx.z;
  const float* Wm = W + (size_t)mat * HDIM * HDIM;
  unsigned short* Wo = Wt + (size_t)mat * mat_stride;
  const int c0 = blockIdx.x * 32, r0 = blockIdx.y * 32;
  const int tx = threadIdx.x & 31, ty = threadIdx.x >> 5;  // 32 x 8
  #pragma unroll
  for (int i = 0; i < 32; i += 8)
    tile[ty + i][tx] = Wm[(size_t)(r0 + ty + i) * HDIM + c0 + tx];
  __syncthreads();
  #pragma unroll
  for (int i = 0; i < 32; i += 8)
    Wo[(size_t)(c0 + ty + i) * HDIM + r0 + tx] = f2bf(tile[tx][ty + i]);
}

// concat biases: bc[layer][512] = [wl_b | wr_b]
__global__ void k_bcat(const float* __restrict__ wl_b, const float* __restrict__ wr_b,
                       float* __restrict__ bc){
  int i = blockIdx.x * 256 + threadIdx.x;   // 4*512
  if (i >= NLAYER * 512) return;
  int layer = i >> 9, c = i & 511;
  bc[i] = (c < 256) ? wl_b[layer * 256 + c] : wr_b[layer * 256 + (c - 256)];
}

// ---------------- MFMA GEMM: C[M,ldc](bf16) = A[M,256](bf16) @ Wt^T + bias
// Wt is [N][256 k] (pre-transposed). 128x128 tile, BK=64, 4 waves (2x2).
__global__ __launch_bounds__(256) void k_gemm_mfma(
    const unsigned short* __restrict__ A, const unsigned short* __restrict__ Wt,
    const float* __restrict__ bias, unsigned short* __restrict__ C, int M, int ldc)
{
  __shared__ unsigned short As[2][128 * 64];
  __shared__ unsigned short Bs[2][128 * 64];
  const int tid = threadIdx.x;
  const int l   = tid & 63;
  const int w   = tid >> 6;           // wave 0..3
  const int wm  = w >> 1, wn = w & 1; // 2x2 wave grid, 64x64 per wave
  const int row0 = blockIdx.x * 128;
  const int col0 = blockIdx.y * 128;

  const int srow   = l >> 3;          // 0..7
  const int schunk = l & 7;           // 16B chunk within 128B row

  f32x4 acc[4][4];
  #pragma unroll
  for (int i = 0; i < 4; ++i)
    #pragma unroll
    for (int j = 0; j < 4; ++j) acc[i][j] = (f32x4){0.f, 0.f, 0.f, 0.f};

  auto stage = [&](int buf, int k0){
    #pragma unroll
    for (int i = 0; i < 4; ++i){
      const int rloc = w * 32 + i * 8 + srow;             // 0..127
      const int sw   = (schunk ^ (rloc & 7)) * 16;        // swizzled 16B chunk
      int ra = row0 + rloc; if (ra > M - 1) ra = M - 1;
      const char* srcA = (const char*)(A + (size_t)ra * HDIM + k0) + sw;
      GLOAD16(srcA, &As[buf][(w * 32 + i * 8) * 64]);
      const char* srcB = (const char*)(Wt + (size_t)(col0 + rloc) * HDIM + k0) + sw;
      GLOAD16(srcB, &Bs[buf][(w * 32 + i * 8) * 64]);
    }
  };

  auto compute = [&](int buf){
    #pragma unroll
    for (int kk = 0; kk < 2; ++kk){
      bf16x8 af[4], bfr[4];
      #pragma unroll
      for (int mi = 0; mi < 4; ++mi){
        const int row = wm * 64 + mi * 16 + (l & 15);
        const int t   = (kk * 4 + (l >> 4)) ^ (row & 7);
        af[mi] = *(const bf16x8*)((const char*)&As[buf][0] + row * 128 + t * 16);
      }
      #pragma unroll
      for (int ni = 0; ni < 4; ++ni){
        const int nn = wn * 64 + ni * 16 + (l & 15);
        const int t  = (kk * 4 + (l >> 4)) ^ (nn & 7);
        bfr[ni] = *(const bf16x8*)((const char*)&Bs[buf][0] + nn * 128 + t * 16);
      }
      #pragma unroll
      for (int mi = 0; mi < 4; ++mi)
        #pragma unroll
        for (int ni = 0; ni < 4; ++ni)
          acc[mi][ni] = __builtin_amdgcn_mfma_f32_16x16x32_bf16(
              af[mi], bfr[ni], acc[mi][ni], 0, 0, 0);
    }
  };

  stage(0, 0);
  int cur = 0;
  #pragma unroll
  for (int t = 0; t < 4; ++t){
    if (t < 3){
      stage(cur ^ 1, (t + 1) * 64);
      asm volatile("s_waitcnt vmcnt(8)" ::: "memory");
    } else {
      asm volatile("s_waitcnt vmcnt(0)" ::: "memory");
    }
    __builtin_amdgcn_s_barrier();
    compute(cur);
    asm volatile("" ::: "memory");
    __builtin_amdgcn_s_barrier();
    cur ^= 1;
  }

  #pragma unroll
  for (int mi = 0; mi < 4; ++mi){
    #pragma unroll
    for (int ni = 0; ni < 4; ++ni){
      const int col = col0 + wn * 64 + ni * 16 + (l & 15);
      const float bv = bias[col];
      #pragma unroll
      for (int r = 0; r < 4; ++r){
        const int row = row0 + wm * 64 + mi * 16 + (l >> 4) * 4 + r;
        if (row < M) C[(size_t)row * ldc + col] = f2bf(acc[mi][ni][r] + bv);
      }
    }
  }
}

// ---------------- fused GATv2 layer: 4-edge-unrolled online softmax + LN + relu
// xlr[node][512]: cols 0..255 = xl, 256..511 = xr. one wave per dst node.
__global__ __launch_bounds__(256) void k_gat(
    const unsigned short* __restrict__ xlr,
    const int* __restrict__ rp, const int* __restrict__ csr,
    const float* __restrict__ att, const float* __restrict__ gb,
    const float* __restrict__ lg, const float* __restrict__ lb,
    const unsigned short* __restrict__ hold, unsigned short* __restrict__ hnew,
    int n, int use_res)
{
  const int node = blockIdx.x * 4 + (threadIdx.x >> 6);
  if (node >= n) return;
  const int lane = threadIdx.x & 63;
  const int elem = lane << 2;
  const int head = lane >> 3;
  float4 attv = *(const float4*)(att + head * HEADD + (elem & 31));
  ushort4 ur = *(const ushort4*)(xlr + (size_t)node * 512 + 256 + elem);
  const float xr0 = bf2f(ur.x), xr1 = bf2f(ur.y), xr2 = bf2f(ur.z), xr3 = bf2f(ur.w);

  auto scoref = [&](ushort4 u)->float{
    float t0 = bf2f(u.x) + xr0; t0 = t0 > 0.f ? t0 : SLOPE * t0;
    float t1 = bf2f(u.y) + xr1; t1 = t1 > 0.f ? t1 : SLOPE * t1;
    float t2 = bf2f(u.z) + xr2; t2 = t2 > 0.f ? t2 : SLOPE * t2;
    float t3 = bf2f(u.w) + xr3; t3 = t3 > 0.f ? t3 : SLOPE * t3;
    float p = attv.x * t0 + attv.y * t1 + attv.z * t2 + attv.w * t3;
    p += __shfl_xor(p, 1);
    p += __shfl_xor(p, 2);
    p += __shfl_xor(p, 4);
    return p;
  };

  float m = -1e30f, l = 0.f, a0 = 0.f, a1 = 0.f, a2 = 0.f, a3 = 0.f;
  const int e0 = rp[node], e1 = rp[node + 1];
  int e = e0;
  for (; e + 4 <= e1; e += 4){
    int s0 = csr[e], s1 = csr[e + 1], s2 = csr[e + 2], s3 = csr[e + 3];
    ushort4 u0 = *(const ushort4*)(xlr + (size_t)s0 * 512 + elem);
    ushort4 u1 = *(const ushort4*)(xlr + (size_t)s1 * 512 + elem);
    ushort4 u2 = *(const ushort4*)(xlr + (size_t)s2 * 512 + elem);
    ushort4 u3 = *(const ushort4*)(xlr + (size_t)s3 * 512 + elem);
    float p0 = scoref(u0), p1 = scoref(u1), p2 = scoref(u2), p3 = scoref(u3);
    float mn = fmaxf(m, fmaxf(fmaxf(p0, p1), fmaxf(p2, p3)));
    float sc = __expf(m - mn);
    float q0 = __expf(p0 - mn), q1 = __expf(p1 - mn);
    float q2 = __expf(p2 - mn), q3 = __expf(p3 - mn);
    l = l * sc + q0 + q1 + q2 + q3;
    a0 = a0 * sc + q0 * bf2f(u0.x) + q1 * bf2f(u1.x) + q2 * bf2f(u2.x) + q3 * bf2f(u3.x);
    a1 = a1 * sc + q0 * bf2f(u0.y) + q1 * bf2f(u1.y) + q2 * bf2f(u2.y) + q3 * bf2f(u3.y);
    a2 = a2 * sc + q0 * bf2f(u0.z) + q1 * bf2f(u1.z) + q2 * bf2f(u2.z) + q3 * bf2f(u3.z);
    a3 = a3 * sc + q0 * bf2f(u0.w) + q1 * bf2f(u1.w) + q2 * bf2f(u2.w) + q3 * bf2f(u3.w);
    m = mn;
  }
  for (; e < e1; ++e){
    int s = csr[e];
    ushort4 u = *(const ushort4*)(xlr + (size_t)s * 512 + elem);
    float p = scoref(u);
    float mn = fmaxf(m, p);
    float sc = __expf(m - mn);
    float pe = __expf(p - mn);
    l  = l * sc + pe;
    a0 = a0 * sc + pe * bf2f(u.x);
    a1 = a1 * sc + pe * bf2f(u.y);
    a2 = a2 * sc + pe * bf2f(u.z);
    a3 = a3 * sc + pe * bf2f(u.w);
    m = mn;
  }
  const float inv = 1.f / l;
  const size_t base = (size_t)node * HDIM + elem;
  float f0 = a0 * inv + gb[elem + 0];
  float f1 = a1 * inv + gb[elem + 1];
  float f2 = a2 * inv + gb[elem + 2];
  float f3 = a3 * inv + gb[elem + 3];
  if (use_res){
    ushort4 hv = *(const ushort4*)(hold + base);
    f0 += bf2f(hv.x); f1 += bf2f(hv.y); f2 += bf2f(hv.z); f3 += bf2f(hv.w);
  }
  float s = f0 + f1 + f2 + f3;
  #pragma unroll
  for (int off = 1; off < 64; off <<= 1) s += __shfl_xor(s, off);
  const float mean = s * (1.f / HDIM);
  float d0 = f0 - mean, d1 = f1 - mean, d2 = f2 - mean, d3 = f3 - mean;
  float q = d0 * d0 + d1 * d1 + d2 * d2 + d3 * d3;
  #pragma unroll
  for (int off = 1; off < 64; off <<= 1) q += __shfl_xor(q, off);
  const float rs = rsqrtf(q * (1.f / HDIM) + EPSN);
  float o0 = d0 * rs * lg[elem + 0] + lb[elem + 0]; o0 = o0 > 0.f ? o0 : 0.f;
  float o1 = d1 * rs * lg[elem + 1] + lb[elem + 1]; o1 = o1 > 0.f ? o1 : 0.f;
  float o2 = d2 * rs * lg[elem + 2] + lb[elem + 2]; o2 = o2 > 0.f ? o2 : 0.f;
  float o3 = d3 * rs * lg[elem + 3] + lb[elem + 3]; o3 = o3 > 0.f ? o3 : 0.f;
  ushort4 st; st.x = f2bf(o0); st.y = f2bf(o1); st.z = f2bf(o2); st.w = f2bf(o3);
  *(ushort4*)(hnew + base) = st;
}

// ---------------- mean pool: batch sorted -> per-graph segment reduce ----------------
__global__ __launch_bounds__(256) void k_pool2(
    const unsigned short* __restrict__ ho, const int* __restrict__ batch,
    float* __restrict__ gr, int n)
{
  const int g = blockIdx.x;
  int lo = 0, hi = n;
  while (lo < hi){ int mid = (lo + hi) >> 1; if (batch[mid] < g) lo = mid + 1; else hi = mid; }
  const int s = lo;
  hi = n;
  while (lo < hi){ int mid = (lo + hi) >> 1; if (batch[mid] < g + 1) lo = mid + 1; else hi = mid; }
  const int e = lo;
  const int j = threadIdx.x;
  float acc = 0.f;
  for (int i = s; i < e; ++i) acc += bf2f(ho[(size_t)i * HDIM + j]);
  int c = e - s; if (c < 1) c = 1;
  gr[(size_t)g * HDIM + j] = acc / (float)c;
}

// ---------------- tiny MLP ----------------
__global__ void k_fc(const float* __restrict__ in, const float* __restrict__ w,
                     const float* __restrict__ b, float* __restrict__ out,
                     int kin, int kout){
  __shared__ float s[256];
  int g = blockIdx.x, j = threadIdx.x;
  for (int k = j; k < kin; k += blockDim.x) s[k] = in[(size_t)g * kin + k];
  __syncthreads();
  float a = b[j];
  for (int k = 0; k < kin; ++k) a = fmaf(s[k], w[k * kout + j], a);
  out[(size_t)g * kout + j] = a;
}
__global__ __launch_bounds__(256) void k_bnstats(const float* __restrict__ z,
    float* __restrict__ mean, float* __restrict__ rstd, int g_, int c_){
  int c = blockIdx.x;
  float s = 0.f, s2 = 0.f;
  for (int r = threadIdx.x; r < g_; r += 256){
    float v = z[(size_t)r * c_ + c];
    s += v; s2 += v * v;
  }
  #pragma unroll
  for (int off = 1; off < 64; off <<= 1){ s += __shfl_xor(s, off); s2 += __shfl_xor(s2, off); }
  __shared__ float sw[4], sw2[4];
  int lane = threadIdx.x & 63, wid = threadIdx.x >> 6;
  if (lane == 0){ sw[wid] = s; sw2[wid] = s2; }
  __syncthreads();
  if (threadIdx.x == 0){
    float ts = sw[0] + sw[1] + sw[2] + sw[3];
    float ts2 = sw2[0] + sw2[1] + sw2[2] + sw2[3];
    float mm = ts / g_;
    float vv = ts2 / g_ - mm * mm;
    mean[c] = mm; rstd[c] = rsqrtf(vv + EPSN);
  }
}
__global__ void k_bnrelu(float* __restrict__ z, const float* __restrict__ mean,
                         const float* __restrict__ rstd, const float* __restrict__ g,
                         const float* __restrict__ b, int total, int c_){
  int i = blockIdx.x * 256 + threadIdx.x;
  if (i < total){
    int c = i & (c_ - 1);
    float v = (z[i] - mean[c]) * rstd[c] * g[c] + b[c];
    z[i] = v > 0.f ? v : 0.f;
  }
}
__global__ __launch_bounds__(256) void k_out(const float* __restrict__ z,
    const float* __restrict__ w, const float* __restrict__ b,
    float* __restrict__ out, int g_){
  int g = blockIdx.x * 4 + (threadIdx.x >> 6);
  if (g >= g_) return;
  int lane = threadIdx.x & 63;
  float v = z[(size_t)g * 64 + lane] * w[lane];
  #pragma unroll
  for (int off = 1; off < 64; off <<= 1) v += __shfl_xor(v, off);
  if (lane == 0) out[g] = v + b[0];
}

// ---------------- host ----------------
extern "C" void kernel_launch(void* const* d_in, const int* in_sizes, int n_in,
                              void* d_out, int out_size, void* d_ws, size_t ws_size,
                              hipStream_t stream)
{
  const float* x     = (const float*)d_in[0];
  const int*   ei    = (const int*)  d_in[1];
  const int*   batch = (const int*)  d_in[2];
  const float* in_w  = (const float*)d_in[3];
  const float* in_b  = (const float*)d_in[4];
  const float* wl    = (const float*)d_in[5];
  const float* wl_b  = (const float*)d_in[6];
  const float* wr    = (const float*)d_in[7];
  const float* wr_b  = (const float*)d_in[8];
  const float* att   = (const float*)d_in[9];
  const float* gat_b = (const float*)d_in[10];
  const float* ln_g  = (const float*)d_in[11];
  const float* ln_b  = (const float*)d_in[12];
  const float* out_w = (const float*)d_in[13];
  const float* out_b = (const float*)d_in[14];
  const float* p1_w  = (const float*)d_in[15];
  const float* p1_b  = (const float*)d_in[16];
  const float* bn1_g = (const float*)d_in[17];
  const float* bn1_b = (const float*)d_in[18];
  const float* p2_w  = (const float*)d_in[19];
  const float* p2_b  = (const float*)d_in[20];
  const float* bn2_g = (const float*)d_in[21];
  const float* bn2_b = (const float*)d_in[22];
  const float* p3_w  = (const float*)d_in[23];
  const float* p3_b  = (const float*)d_in[24];

  const int n = in_sizes[0] / F_IN;     // 50000
  const int e = in_sizes[1] / 2;        // 800000
  const int g = out_size;               // 500
  const int nb = (n + 255) / 256;       // scan blocks

  char* p = (char*)d_ws;
  auto take = [&](size_t bytes)->char*{
    char* q = p; p += ((bytes + 255) & ~(size_t)255); return q;
  };
  unsigned short* hA   = (unsigned short*)take((size_t)n * HDIM * 2);
  unsigned short* hB   = (unsigned short*)take((size_t)n * HDIM * 2);
  unsigned short* xlr  = (unsigned short*)take((size_t)n * 512 * 2);
  unsigned short* WtLR = (unsigned short*)take((size_t)NLAYER * 512 * HDIM * 2);
  unsigned short* WtO  = (unsigned short*)take((size_t)HDIM * HDIM * 2);
  float* bconc = (float*)take((size_t)NLAYER * 512 * 4);
  int*   deg   = (int*)take((size_t)n * 4);
  int*   rowp  = (int*)take((size_t)(n + 1) * 4);
  int*   cur   = (int*)take((size_t)n * 4);
  int*   csr   = (int*)take((size_t)(e + n) * 4);
  int*   bsum  = (int*)take((size_t)(nb + 1) * 4);
  int*   boff  = (int*)take((size_t)(nb + 1) * 4);
  float* gr    = (float*)take((size_t)g * HDIM * 4);
  float* z1    = (float*)take((size_t)g * 128 * 4);
  float* z2    = (float*)take((size_t)g * 64 * 4);
  float* mean1 = (float*)take(128 * 4);
  float* rstd1 = (float*)take(128 * 4);
  float* mean2 = (float*)take(64 * 4);
  float* rstd2 = (float*)take(64 * 4);
  (void)ws_size; (void)n_in;

  // CSR build
  hipMemsetAsync(deg, 0, (size_t)n * 4, stream);
  k_hist<<<(e + 255) / 256, 256, 0, stream>>>(ei + e, deg, e);
  k_scan1<<<nb, 256, 0, stream>>>(deg, rowp, bsum, n);
  k_scan2<<<1, 256, 0, stream>>>(bsum, boff, nb);
  k_scan3<<<nb, 256, 0, stream>>>(rowp, boff, n, nb);
  k_copy<<<(n + 255) / 256, 256, 0, stream>>>(rowp, cur, n);
  k_fill<<<(e + 255) / 256, 256, 0, stream>>>(ei, ei + e, cur, csr, e);
  k_fillself<<<(n + 255) / 256, 256, 0, stream>>>(cur, csr, n);

  // weight conversion (transpose + bf16); WtLR layer layout: [512 rows][256 k]
  k_wconv<<<dim3(8, 8, 4), 256, 0, stream>>>(wl, WtLR, (size_t)512 * HDIM);
  k_wconv<<<dim3(8, 8, 4), 256, 0, stream>>>(wr, WtLR + (size_t)256 * HDIM, (size_t)512 * HDIM);
  k_wconv<<<dim3(8, 8, 1), 256, 0, stream>>>(out_w, WtO, (size_t)HDIM * HDIM);
  k_bcat<<<(NLAYER * 512 + 255) / 256, 256, 0, stream>>>(wl_b, wr_b, bconc);

  // input projection
  k_inproj<<<(n + 31) / 32, 256, 0, stream>>>(x, in_w, in_b, hA, n);

  unsigned short* hcur = hA;
  unsigned short* hnext = hB;
  for (int i = 0; i < NLAYER; ++i){
    k_gemm_mfma<<<dim3((n + 127) / 128, 4), 256, 0, stream>>>(
        hcur, WtLR + (size_t)i * 512 * HDIM, bconc + i * 512, xlr, n, 512);
    k_gat<<<(n + 3) / 4, 256, 0, stream>>>(xlr, rowp, csr,
        att + (size_t)i * NHEAD * HEADD, gat_b + i * HDIM,
        ln_g + i * HDIM, ln_b + i * HDIM, hcur, hnext, n, i > 0 ? 1 : 0);
    unsigned short* t = hcur; hcur = hnext; hnext = t;
  }
  // output projection: hcur == hA after 4 swaps; write into hB
  k_gemm_mfma<<<dim3((n + 127) / 128, 2), 256, 0, stream>>>(
      hcur, WtO, out_b, hnext, n, HDIM);

  // pooling (batch sorted -> segment reduce)
  k_pool2<<<g, 256, 0, stream>>>(hnext, batch, gr, n);

  // MLP head
  k_fc<<<g, 128, 0, stream>>>(gr, p1_w, p1_b, z1, HDIM, 128);
  k_bnstats<<<128, 256, 0, stream>>>(z1, mean1, rstd1, g, 128);
  k_bnrelu<<<(g * 128 + 255) / 256, 256, 0, stream>>>(z1, mean1, rstd1, bn1_g, bn1_b, g * 128, 128);
  k_fc<<<g, 64, 0, stream>>>(z1, p2_w, p2_b, z2, 128, 64);
  k_bnstats<<<64, 256, 0, stream>>>(z2, mean2, rstd2, g, 64);
  k_bnrelu<<<(g * 64 + 255) / 256, 256, 0, stream>>>(z2, mean2, rstd2, bn2_g, bn2_b, g * 64, 64);
  k_out<<<(g + 3) / 4, 256, 0, stream>>>(z2, p3_w, p3_b, (float*)d_out, g);
}

// Round 4
// 707.612 us; speedup vs baseline: 2.4943x; 1.0713x over previous
//
#include <hip/hip_runtime.h>
#include <hip/hip_bf16.h>

#define F_IN   74
#define KPAD   96
#define HDIM   256
#define NHEAD  8
#define HEADD  32
#define NLAYER 4
#define SLOPE  0.2f
#define EPSN   1e-5f

typedef __attribute__((ext_vector_type(8))) short bf16x8;
typedef __attribute__((ext_vector_type(4))) float f32x4;

__device__ __forceinline__ float bf2f(unsigned short u){
  union { unsigned int i; float f; } x; x.i = ((unsigned int)u) << 16; return x.f;
}
__device__ __forceinline__ unsigned short f2bf(float f){
  union { float f; unsigned int i; } x; x.f = f;
  unsigned int u = x.i;
  return (unsigned short)((u + 0x7FFFu + ((u >> 16) & 1u)) >> 16);
}

#define GLOAD16(g, s) __builtin_amdgcn_global_load_lds( \
  (const __attribute__((address_space(1))) void*)(g), \
  (__attribute__((address_space(3))) void*)(s), 16, 0, 0)

// ---------------- CSR build (dst-grouped) ----------------
__global__ void k_hist(const int* __restrict__ dst, int* __restrict__ deg, int e){
  int i = blockIdx.x * 256 + threadIdx.x;
  if (i < e) atomicAdd(&deg[dst[i]], 1);
}

__global__ __launch_bounds__(256) void k_scan1(const int* __restrict__ deg,
    int* __restrict__ rowp, int* __restrict__ bsum, int n){
  __shared__ int wsum[4];
  const int tid = threadIdx.x, lane = tid & 63, wid = tid >> 6;
  const int i = blockIdx.x * 256 + tid;
  int v = (i < n) ? (deg[i] + 1) : 0;   // +1 self-loop
  int xv = v;
  #pragma unroll
  for (int off = 1; off < 64; off <<= 1){
    int t = __shfl_up(xv, off);
    if (lane >= off) xv += t;
  }
  if (lane == 63) wsum[wid] = xv;
  __syncthreads();
  int woff = 0, total = 0;
  #pragma unroll
  for (int w = 0; w < 4; ++w){
    int s = wsum[w];
    total += s;
    if (w < wid) woff += s;
  }
  if (i < n) rowp[i] = woff + xv - v;    // local exclusive
  if (tid == 0) bsum[blockIdx.x] = total;
}
__global__ __launch_bounds__(256) void k_scan2(const int* __restrict__ bsum,
    int* __restrict__ boff, int nb){
  __shared__ int wsum[4];
  const int tid = threadIdx.x, lane = tid & 63, wid = tid >> 6;
  int v = (tid < nb) ? bsum[tid] : 0;
  int xv = v;
  #pragma unroll
  for (int off = 1; off < 64; off <<= 1){
    int t = __shfl_up(xv, off);
    if (lane >= off) xv += t;
  }
  if (lane == 63) wsum[wid] = xv;
  __syncthreads();
  int woff = 0, total = 0;
  #pragma unroll
  for (int w = 0; w < 4; ++w){
    int s = wsum[w];
    total += s;
    if (w < wid) woff += s;
  }
  if (tid <= nb) boff[tid] = woff + xv - v;
  if (tid == 0) boff[nb] = total;
}
__global__ void k_scan3(int* __restrict__ rowp, int* __restrict__ cur,
                        const int* __restrict__ boff, int n, int nb){
  int i = blockIdx.x * 256 + threadIdx.x;
  if (i < n){
    int v = rowp[i] + boff[blockIdx.x];
    rowp[i] = v;
    cur[i] = v;
  }
  if (i == 0) rowp[n] = boff[nb];
}

__global__ void k_fill(const int* __restrict__ src, const int* __restrict__ dst,
                       int* __restrict__ cur, int* __restrict__ csr, int e){
  int i = blockIdx.x * 256 + threadIdx.x;
  if (i < e){
    int p = atomicAdd(&cur[dst[i]], 1);
    csr[p] = src[i];
  }
}
__global__ void k_fillself(int* __restrict__ cur, int* __restrict__ csr, int n){
  int i = blockIdx.x * 256 + threadIdx.x;
  if (i < n){
    int p = atomicAdd(&cur[i], 1);
    csr[p] = i;
  }
}

// ---------------- x convert: xb[n][96] (bf16, zero-pad) = x[n][74] ----------------
__global__ void k_xconv(const float* __restrict__ x, unsigned short* __restrict__ xb,
                        int n){
  int idx = blockIdx.x * 256 + threadIdx.x;
  int total = n * KPAD;
  if (idx >= total) return;
  int row = idx / KPAD;
  int k = idx - row * KPAD;
  float v = (k < F_IN) ? x[(size_t)row * F_IN + k] : 0.f;
  xb[idx] = f2bf(v);
}

// in_w [74][256] -> Wt_in [256][96] bf16 transposed+padded
__global__ void k_wconv_in(const float* __restrict__ w, unsigned short* __restrict__ Wt){
  int idx = blockIdx.x * 256 + threadIdx.x;   // 256*96
  if (idx >= HDIM * KPAD) return;
  int c = idx / KPAD;
  int k = idx - c * KPAD;
  float v = (k < F_IN) ? w[(size_t)k * HDIM + c] : 0.f;
  Wt[idx] = f2bf(v);
}

// ---------------- input projection via MFMA, K=96, no LDS ----------------
__global__ __launch_bounds__(256) void k_inproj_mfma(
    const unsigned short* __restrict__ xb, const unsigned short* __restrict__ Wt,
    const float* __restrict__ bias, unsigned short* __restrict__ C, int M)
{
  const int l = threadIdx.x & 63;
  const int w = threadIdx.x >> 6;
  const int wm = w >> 1, wn = w & 1;
  const int row0 = blockIdx.x * 128;
  const int col0 = blockIdx.y * 128;

  f32x4 acc[4][4];
  #pragma unroll
  for (int i = 0; i < 4; ++i)
    #pragma unroll
    for (int j = 0; j < 4; ++j) acc[i][j] = (f32x4){0.f, 0.f, 0.f, 0.f};

  #pragma unroll
  for (int kk = 0; kk < 3; ++kk){
    const int kof = kk * 32 + (l >> 4) * 8;
    bf16x8 af[4], bfr[4];
    #pragma unroll
    for (int mi = 0; mi < 4; ++mi){
      int row = row0 + wm * 64 + mi * 16 + (l & 15);
      if (row > M - 1) row = M - 1;
      af[mi] = *(const bf16x8*)(xb + (size_t)row * KPAD + kof);
    }
    #pragma unroll
    for (int ni = 0; ni < 4; ++ni){
      const int col = col0 + wn * 64 + ni * 16 + (l & 15);
      bfr[ni] = *(const bf16x8*)(Wt + (size_t)col * KPAD + kof);
    }
    #pragma unroll
    for (int mi = 0; mi < 4; ++mi)
      #pragma unroll
      for (int ni = 0; ni < 4; ++ni)
        acc[mi][ni] = __builtin_amdgcn_mfma_f32_16x16x32_bf16(
            af[mi], bfr[ni], acc[mi][ni], 0, 0, 0);
  }

  #pragma unroll
  for (int mi = 0; mi < 4; ++mi){
    #pragma unroll
    for (int ni = 0; ni < 4; ++ni){
      const int col = col0 + wn * 64 + ni * 16 + (l & 15);
      const float bv = bias[col];
      #pragma unroll
      for (int r = 0; r < 4; ++r){
        const int row = row0 + wm * 64 + mi * 16 + (l >> 4) * 4 + r;
        if (row < M) C[(size_t)row * HDIM + col] = f2bf(acc[mi][ni][r] + bv);
      }
    }
  }
}

// ---------------- weight convert: Wt[n][k] = (bf16)W[k][n], strided output ----------------
__global__ __launch_bounds__(256) void k_wconv(const float* __restrict__ W,
    unsigned short* __restrict__ Wt, size_t mat_stride){
  __shared__ float tile[32][33];
  const int mat = blockIdx.z;
  const float* Wm = W + (size_t)mat * HDIM * HDIM;
  unsigned short* Wo = Wt + (size_t)mat * mat_stride;
  const int c0 = blockIdx.x * 32, r0 = blockIdx.y * 32;
  const int tx = threadIdx.x & 31, ty = threadIdx.x >> 5;  // 32 x 8
  #pragma unroll
  for (int i = 0; i < 32; i += 8)
    tile[ty + i][tx] = Wm[(size_t)(r0 + ty + i) * HDIM + c0 + tx];
  __syncthreads();
  #pragma unroll
  for (int i = 0; i < 32; i += 8)
    Wo[(size_t)(c0 + ty + i) * HDIM + r0 + tx] = f2bf(tile[tx][ty + i]);
}

// concat biases: bc[layer][512] = [wl_b | wr_b]
__global__ void k_bcat(const float* __restrict__ wl_b, const float* __restrict__ wr_b,
                       float* __restrict__ bc){
  int i = blockIdx.x * 256 + threadIdx.x;
  if (i >= NLAYER * 512) return;
  int layer = i >> 9, c = i & 511;
  bc[i] = (c < 256) ? wl_b[layer * 256 + c] : wr_b[layer * 256 + (c - 256)];
}

// ---------------- MFMA GEMM: C[M,ldc](bf16) = A[M,256](bf16) @ Wt^T + bias ----------------
__global__ __launch_bounds__(256) void k_gemm_mfma(
    const unsigned short* __restrict__ A, const unsigned short* __restrict__ Wt,
    const float* __restrict__ bias, unsigned short* __restrict__ C, int M, int ldc)
{
  __shared__ unsigned short As[2][128 * 64];
  __shared__ unsigned short Bs[2][128 * 64];
  const int tid = threadIdx.x;
  const int l   = tid & 63;
  const int w   = tid >> 6;
  const int wm  = w >> 1, wn = w & 1;
  const int row0 = blockIdx.x * 128;
  const int col0 = blockIdx.y * 128;

  const int srow   = l >> 3;
  const int schunk = l & 7;

  f32x4 acc[4][4];
  #pragma unroll
  for (int i = 0; i < 4; ++i)
    #pragma unroll
    for (int j = 0; j < 4; ++j) acc[i][j] = (f32x4){0.f, 0.f, 0.f, 0.f};

  auto stage = [&](int buf, int k0){
    #pragma unroll
    for (int i = 0; i < 4; ++i){
      const int rloc = w * 32 + i * 8 + srow;
      const int sw   = (schunk ^ (rloc & 7)) * 16;
      int ra = row0 + rloc; if (ra > M - 1) ra = M - 1;
      const char* srcA = (const char*)(A + (size_t)ra * HDIM + k0) + sw;
      GLOAD16(srcA, &As[buf][(w * 32 + i * 8) * 64]);
      const char* srcB = (const char*)(Wt + (size_t)(col0 + rloc) * HDIM + k0) + sw;
      GLOAD16(srcB, &Bs[buf][(w * 32 + i * 8) * 64]);
    }
  };

  auto compute = [&](int buf){
    #pragma unroll
    for (int kk = 0; kk < 2; ++kk){
      bf16x8 af[4], bfr[4];
      #pragma unroll
      for (int mi = 0; mi < 4; ++mi){
        const int row = wm * 64 + mi * 16 + (l & 15);
        const int t   = (kk * 4 + (l >> 4)) ^ (row & 7);
        af[mi] = *(const bf16x8*)((const char*)&As[buf][0] + row * 128 + t * 16);
      }
      #pragma unroll
      for (int ni = 0; ni < 4; ++ni){
        const int nn = wn * 64 + ni * 16 + (l & 15);
        const int t  = (kk * 4 + (l >> 4)) ^ (nn & 7);
        bfr[ni] = *(const bf16x8*)((const char*)&Bs[buf][0] + nn * 128 + t * 16);
      }
      #pragma unroll
      for (int mi = 0; mi < 4; ++mi)
        #pragma unroll
        for (int ni = 0; ni < 4; ++ni)
          acc[mi][ni] = __builtin_amdgcn_mfma_f32_16x16x32_bf16(
              af[mi], bfr[ni], acc[mi][ni], 0, 0, 0);
    }
  };

  stage(0, 0);
  int cur = 0;
  #pragma unroll
  for (int t = 0; t < 4; ++t){
    if (t < 3){
      stage(cur ^ 1, (t + 1) * 64);
      asm volatile("s_waitcnt vmcnt(8)" ::: "memory");
    } else {
      asm volatile("s_waitcnt vmcnt(0)" ::: "memory");
    }
    __builtin_amdgcn_s_barrier();
    compute(cur);
    asm volatile("" ::: "memory");
    __builtin_amdgcn_s_barrier();
    cur ^= 1;
  }

  #pragma unroll
  for (int mi = 0; mi < 4; ++mi){
    #pragma unroll
    for (int ni = 0; ni < 4; ++ni){
      const int col = col0 + wn * 64 + ni * 16 + (l & 15);
      const float bv = bias[col];
      #pragma unroll
      for (int r = 0; r < 4; ++r){
        const int row = row0 + wm * 64 + mi * 16 + (l >> 4) * 4 + r;
        if (row < M) C[(size_t)row * ldc + col] = f2bf(acc[mi][ni][r] + bv);
      }
    }
  }
}

// ---------------- fused GATv2: no-max softmax (scores bounded) + LN + relu ----------------
__global__ __launch_bounds__(256) void k_gat(
    const unsigned short* __restrict__ xlr,
    const int* __restrict__ rp, const int* __restrict__ csr,
    const float* __restrict__ att, const float* __restrict__ gb,
    const float* __restrict__ lg, const float* __restrict__ lb,
    const unsigned short* __restrict__ hold, unsigned short* __restrict__ hnew,
    int n, int use_res)
{
  const int node = blockIdx.x * 4 + (threadIdx.x >> 6);
  if (node >= n) return;
  const int lane = threadIdx.x & 63;
  const int elem = lane << 2;
  const int head = lane >> 3;
  float4 attv = *(const float4*)(att + head * HEADD + (elem & 31));
  ushort4 ur = *(const ushort4*)(xlr + (size_t)node * 512 + 256 + elem);
  const float xr0 = bf2f(ur.x), xr1 = bf2f(ur.y), xr2 = bf2f(ur.z), xr3 = bf2f(ur.w);

  auto scoref = [&](ushort4 u)->float{
    float t0 = bf2f(u.x) + xr0; t0 = t0 > 0.f ? t0 : SLOPE * t0;
    float t1 = bf2f(u.y) + xr1; t1 = t1 > 0.f ? t1 : SLOPE * t1;
    float t2 = bf2f(u.z) + xr2; t2 = t2 > 0.f ? t2 : SLOPE * t2;
    float t3 = bf2f(u.w) + xr3; t3 = t3 > 0.f ? t3 : SLOPE * t3;
    float p = attv.x * t0 + attv.y * t1 + attv.z * t2 + attv.w * t3;
    p += __shfl_xor(p, 1);
    p += __shfl_xor(p, 2);
    p += __shfl_xor(p, 4);
    return p;
  };

  float l = 0.f, a0 = 0.f, a1 = 0.f, a2 = 0.f, a3 = 0.f;
  const int e0 = rp[node], e1 = rp[node + 1];
  int e = e0;
  for (; e + 4 <= e1; e += 4){
    int s0 = csr[e], s1 = csr[e + 1], s2 = csr[e + 2], s3 = csr[e + 3];
    ushort4 u0 = *(const ushort4*)(xlr + (size_t)s0 * 512 + elem);
    ushort4 u1 = *(const ushort4*)(xlr + (size_t)s1 * 512 + elem);
    ushort4 u2 = *(const ushort4*)(xlr + (size_t)s2 * 512 + elem);
    ushort4 u3 = *(const ushort4*)(xlr + (size_t)s3 * 512 + elem);
    float q0 = __expf(scoref(u0)), q1 = __expf(scoref(u1));
    float q2 = __expf(scoref(u2)), q3 = __expf(scoref(u3));
    l += q0 + q1 + q2 + q3;
    a0 += q0 * bf2f(u0.x) + q1 * bf2f(u1.x) + q2 * bf2f(u2.x) + q3 * bf2f(u3.x);
    a1 += q0 * bf2f(u0.y) + q1 * bf2f(u1.y) + q2 * bf2f(u2.y) + q3 * bf2f(u3.y);
    a2 += q0 * bf2f(u0.z) + q1 * bf2f(u1.z) + q2 * bf2f(u2.z) + q3 * bf2f(u3.z);
    a3 += q0 * bf2f(u0.w) + q1 * bf2f(u1.w) + q2 * bf2f(u2.w) + q3 * bf2f(u3.w);
  }
  for (; e < e1; ++e){
    int s = csr[e];
    ushort4 u = *(const ushort4*)(xlr + (size_t)s * 512 + elem);
    float q = __expf(scoref(u));
    l  += q;
    a0 += q * bf2f(u.x);
    a1 += q * bf2f(u.y);
    a2 += q * bf2f(u.z);
    a3 += q * bf2f(u.w);
  }
  const float inv = 1.f / l;
  const size_t base = (size_t)node * HDIM + elem;
  float f0 = a0 * inv + gb[elem + 0];
  float f1 = a1 * inv + gb[elem + 1];
  float f2 = a2 * inv + gb[elem + 2];
  float f3 = a3 * inv + gb[elem + 3];
  if (use_res){
    ushort4 hv = *(const ushort4*)(hold + base);
    f0 += bf2f(hv.x); f1 += bf2f(hv.y); f2 += bf2f(hv.z); f3 += bf2f(hv.w);
  }
  float s = f0 + f1 + f2 + f3;
  #pragma unroll
  for (int off = 1; off < 64; off <<= 1) s += __shfl_xor(s, off);
  const float mean = s * (1.f / HDIM);
  float d0 = f0 - mean, d1 = f1 - mean, d2 = f2 - mean, d3 = f3 - mean;
  float q = d0 * d0 + d1 * d1 + d2 * d2 + d3 * d3;
  #pragma unroll
  for (int off = 1; off < 64; off <<= 1) q += __shfl_xor(q, off);
  const float rs = rsqrtf(q * (1.f / HDIM) + EPSN);
  float o0 = d0 * rs * lg[elem + 0] + lb[elem + 0]; o0 = o0 > 0.f ? o0 : 0.f;
  float o1 = d1 * rs * lg[elem + 1] + lb[elem + 1]; o1 = o1 > 0.f ? o1 : 0.f;
  float o2 = d2 * rs * lg[elem + 2] + lb[elem + 2]; o2 = o2 > 0.f ? o2 : 0.f;
  float o3 = d3 * rs * lg[elem + 3] + lb[elem + 3]; o3 = o3 > 0.f ? o3 : 0.f;
  ushort4 st; st.x = f2bf(o0); st.y = f2bf(o1); st.z = f2bf(o2); st.w = f2bf(o3);
  *(ushort4*)(hnew + base) = st;
}

// ---------------- mean pool: batch sorted -> per-graph segment reduce ----------------
__global__ __launch_bounds__(256) void k_pool2(
    const unsigned short* __restrict__ ho, const int* __restrict__ batch,
    float* __restrict__ gr, int n)
{
  const int g = blockIdx.x;
  int lo = 0, hi = n;
  while (lo < hi){ int mid = (lo + hi) >> 1; if (batch[mid] < g) lo = mid + 1; else hi = mid; }
  const int s = lo;
  hi = n;
  while (lo < hi){ int mid = (lo + hi) >> 1; if (batch[mid] < g + 1) lo = mid + 1; else hi = mid; }
  const int e = lo;
  const int j = threadIdx.x;
  float acc = 0.f;
  for (int i = s; i < e; ++i) acc += bf2f(ho[(size_t)i * HDIM + j]);
  int c = e - s; if (c < 1) c = 1;
  gr[(size_t)g * HDIM + j] = acc / (float)c;
}

// ---------------- tiny MLP ----------------
__global__ void k_fc(const float* __restrict__ in, const float* __restrict__ w,
                     const float* __restrict__ b, float* __restrict__ out,
                     int kin, int kout){
  __shared__ float s[256];
  int g = blockIdx.x, j = threadIdx.x;
  for (int k = j; k < kin; k += blockDim.x) s[k] = in[(size_t)g * kin + k];
  __syncthreads();
  float a = b[j];
  for (int k = 0; k < kin; ++k) a = fmaf(s[k], w[k * kout + j], a);
  out[(size_t)g * kout + j] = a;
}
__global__ __launch_bounds__(256) void k_bnstats(const float* __restrict__ z,
    float* __restrict__ mean, float* __restrict__ rstd, int g_, int c_){
  int c = blockIdx.x;
  float s = 0.f, s2 = 0.f;
  for (int r = threadIdx.x; r < g_; r += 256){
    float v = z[(size_t)r * c_ + c];
    s += v; s2 += v * v;
  }
  #pragma unroll
  for (int off = 1; off < 64; off <<= 1){ s += __shfl_xor(s, off); s2 += __shfl_xor(s2, off); }
  __shared__ float sw[4], sw2[4];
  int lane = threadIdx.x & 63, wid = threadIdx.x >> 6;
  if (lane == 0){ sw[wid] = s; sw2[wid] = s2; }
  __syncthreads();
  if (threadIdx.x == 0){
    float ts = sw[0] + sw[1] + sw[2] + sw[3];
    float ts2 = sw2[0] + sw2[1] + sw2[2] + sw2[3];
    float mm = ts / g_;
    float vv = ts2 / g_ - mm * mm;
    mean[c] = mm; rstd[c] = rsqrtf(vv + EPSN);
  }
}
__global__ void k_bnrelu(float* __restrict__ z, const float* __restrict__ mean,
                         const float* __restrict__ rstd, const float* __restrict__ g,
                         const float* __restrict__ b, int total, int c_){
  int i = blockIdx.x * 256 + threadIdx.x;
  if (i < total){
    int c = i & (c_ - 1);
    float v = (z[i] - mean[c]) * rstd[c] * g[c] + b[c];
    z[i] = v > 0.f ? v : 0.f;
  }
}
__global__ __launch_bounds__(256) void k_out(const float* __restrict__ z,
    const float* __restrict__ w, const float* __restrict__ b,
    float* __restrict__ out, int g_){
  int g = blockIdx.x * 4 + (threadIdx.x >> 6);
  if (g >= g_) return;
  int lane = threadIdx.x & 63;
  float v = z[(size_t)g * 64 + lane] * w[lane];
  #pragma unroll
  for (int off = 1; off < 64; off <<= 1) v += __shfl_xor(v, off);
  if (lane == 0) out[g] = v + b[0];
}

// ---------------- host ----------------
extern "C" void kernel_launch(void* const* d_in, const int* in_sizes, int n_in,
                              void* d_out, int out_size, void* d_ws, size_t ws_size,
                              hipStream_t stream)
{
  const float* x     = (const float*)d_in[0];
  const int*   ei    = (const int*)  d_in[1];
  const int*   batch = (const int*)  d_in[2];
  const float* in_w  = (const float*)d_in[3];
  const float* in_b  = (const float*)d_in[4];
  const float* wl    = (const float*)d_in[5];
  const float* wl_b  = (const float*)d_in[6];
  const float* wr    = (const float*)d_in[7];
  const float* wr_b  = (const float*)d_in[8];
  const float* att   = (const float*)d_in[9];
  const float* gat_b = (const float*)d_in[10];
  const float* ln_g  = (const float*)d_in[11];
  const float* ln_b  = (const float*)d_in[12];
  const float* out_w = (const float*)d_in[13];
  const float* out_b = (const float*)d_in[14];
  const float* p1_w  = (const float*)d_in[15];
  const float* p1_b  = (const float*)d_in[16];
  const float* bn1_g = (const float*)d_in[17];
  const float* bn1_b = (const float*)d_in[18];
  const float* p2_w  = (const float*)d_in[19];
  const float* p2_b  = (const float*)d_in[20];
  const float* bn2_g = (const float*)d_in[21];
  const float* bn2_b = (const float*)d_in[22];
  const float* p3_w  = (const float*)d_in[23];
  const float* p3_b  = (const float*)d_in[24];

  const int n = in_sizes[0] / F_IN;     // 50000
  const int e = in_sizes[1] / 2;        // 800000
  const int g = out_size;               // 500
  const int nb = (n + 255) / 256;

  char* p = (char*)d_ws;
  auto take = [&](size_t bytes)->char*{
    char* q = p; p += ((bytes + 255) & ~(size_t)255); return q;
  };
  unsigned short* hA   = (unsigned short*)take((size_t)n * HDIM * 2);
  unsigned short* hB   = (unsigned short*)take((size_t)n * HDIM * 2);
  unsigned short* xlr  = (unsigned short*)take((size_t)n * 512 * 2);
  unsigned short* WtLR = (unsigned short*)take((size_t)NLAYER * 512 * HDIM * 2);
  unsigned short* WtO  = (unsigned short*)take((size_t)HDIM * HDIM * 2);
  unsigned short* WtI  = (unsigned short*)take((size_t)HDIM * KPAD * 2);
  float* bconc = (float*)take((size_t)NLAYER * 512 * 4);
  int*   deg   = (int*)take((size_t)n * 4);
  int*   rowp  = (int*)take((size_t)(n + 1) * 4);
  int*   cur   = (int*)take((size_t)n * 4);
  int*   csr   = (int*)take((size_t)(e + n) * 4);
  int*   bsum  = (int*)take((size_t)(nb + 1) * 4);
  int*   boff  = (int*)take((size_t)(nb + 1) * 4);
  float* gr    = (float*)take((size_t)g * HDIM * 4);
  float* z1    = (float*)take((size_t)g * 128 * 4);
  float* z2    = (float*)take((size_t)g * 64 * 4);
  float* mean1 = (float*)take(128 * 4);
  float* rstd1 = (float*)take(128 * 4);
  float* mean2 = (float*)take(64 * 4);
  float* rstd2 = (float*)take(64 * 4);
  // xb aliases xlr (xb only needed before first GEMM writes xlr)
  unsigned short* xb = xlr;
  (void)ws_size; (void)n_in;

  // CSR build
  hipMemsetAsync(deg, 0, (size_t)n * 4, stream);
  k_hist<<<(e + 255) / 256, 256, 0, stream>>>(ei + e, deg, e);
  k_scan1<<<nb, 256, 0, stream>>>(deg, rowp, bsum, n);
  k_scan2<<<1, 256, 0, stream>>>(bsum, boff, nb);
  k_scan3<<<nb, 256, 0, stream>>>(rowp, cur, boff, n, nb);
  k_fill<<<(e + 255) / 256, 256, 0, stream>>>(ei, ei + e, cur, csr, e);
  k_fillself<<<(n + 255) / 256, 256, 0, stream>>>(cur, csr, n);

  // weight conversion
  k_wconv<<<dim3(8, 8, 4), 256, 0, stream>>>(wl, WtLR, (size_t)512 * HDIM);
  k_wconv<<<dim3(8, 8, 4), 256, 0, stream>>>(wr, WtLR + (size_t)256 * HDIM, (size_t)512 * HDIM);
  k_wconv<<<dim3(8, 8, 1), 256, 0, stream>>>(out_w, WtO, (size_t)HDIM * HDIM);
  k_wconv_in<<<(HDIM * KPAD + 255) / 256, 256, 0, stream>>>(in_w, WtI);
  k_bcat<<<(NLAYER * 512 + 255) / 256, 256, 0, stream>>>(wl_b, wr_b, bconc);

  // input projection (MFMA, K=96)
  k_xconv<<<((n * KPAD) + 255) / 256, 256, 0, stream>>>(x, xb, n);
  k_inproj_mfma<<<dim3((n + 127) / 128, 2), 256, 0, stream>>>(xb, WtI, in_b, hA, n);

  unsigned short* hcur = hA;
  unsigned short* hnext = hB;
  for (int i = 0; i < NLAYER; ++i){
    k_gemm_mfma<<<dim3((n + 127) / 128, 4), 256, 0, stream>>>(
        hcur, WtLR + (size_t)i * 512 * HDIM, bconc + i * 512, xlr, n, 512);
    k_gat<<<(n + 3) / 4, 256, 0, stream>>>(xlr, rowp, csr,
        att + (size_t)i * NHEAD * HEADD, gat_b + i * HDIM,
        ln_g + i * HDIM, ln_b + i * HDIM, hcur, hnext, n, i > 0 ? 1 : 0);
    unsigned short* t = hcur; hcur = hnext; hnext = t;
  }
  // output projection
  k_gemm_mfma<<<dim3((n + 127) / 128, 2), 256, 0, stream>>>(
      hcur, WtO, out_b, hnext, n, HDIM);

  // pooling
  k_pool2<<<g, 256, 0, stream>>>(hnext, batch, gr, n);

  // MLP head
  k_fc<<<g, 128, 0, stream>>>(gr, p1_w, p1_b, z1, HDIM, 128);
  k_bnstats<<<128, 256, 0, stream>>>(z1, mean1, rstd1, g, 128);
  k_bnrelu<<<(g * 128 + 255) / 256, 256, 0, stream>>>(z1, mean1, rstd1, bn1_g, bn1_b, g * 128, 128);
  k_fc<<<g, 64, 0, stream>>>(z1, p2_w, p2_b, z2, 128, 64);
  k_bnstats<<<64, 256, 0, stream>>>(z2, mean2, rstd2, g, 64);
  k_bnrelu<<<(g * 64 + 255) / 256, 256, 0, stream>>>(z2, mean2, rstd2, bn2_g, bn2_b, g * 64, 64);
  k_out<<<(g + 3) / 4, 256, 0, stream>>>(z2, p3_w, p3_b, (float*)d_out, g);
}

// Round 5
// 703.199 us; speedup vs baseline: 2.5099x; 1.0063x over previous
//
#include <hip/hip_runtime.h>
#include <hip/hip_bf16.h>

#define F_IN   74
#define KPAD   96
#define HDIM   256
#define NHEAD  8
#define HEADD  32
#define NLAYER 4
#define SLOPE  0.2f
#define EPSN   1e-5f

typedef __attribute__((ext_vector_type(8))) short bf16x8;
typedef __attribute__((ext_vector_type(4))) float f32x4;
typedef __attribute__((ext_vector_type(2))) float f32x2;

__device__ __forceinline__ float bf2f(unsigned short u){
  union { unsigned int i; float f; } x; x.i = ((unsigned int)u) << 16; return x.f;
}
__device__ __forceinline__ unsigned short f2bf(float f){
  union { float f; unsigned int i; } x; x.f = f;
  unsigned int u = x.i;
  return (unsigned short)((u + 0x7FFFu + ((u >> 16) & 1u)) >> 16);
}
// unpack 2 bf16 (packed in u32) -> f32x2
__device__ __forceinline__ f32x2 bfpair(unsigned int u){
  union { unsigned int i; float f; } lo, hi;
  lo.i = u << 16; hi.i = u & 0xffff0000u;
  return (f32x2){lo.f, hi.f};
}

#define GLOAD16(g, s) __builtin_amdgcn_global_load_lds( \
  (const __attribute__((address_space(1))) void*)(g), \
  (__attribute__((address_space(3))) void*)(s), 16, 0, 0)

// ---------------- CSR build (dst-grouped) ----------------
__global__ void k_hist(const int* __restrict__ dst, int* __restrict__ deg, int e){
  int i = blockIdx.x * 256 + threadIdx.x;
  if (i < e) atomicAdd(&deg[dst[i]], 1);
}

__global__ __launch_bounds__(256) void k_scan1(const int* __restrict__ deg,
    int* __restrict__ rowp, int* __restrict__ bsum, int n){
  __shared__ int wsum[4];
  const int tid = threadIdx.x, lane = tid & 63, wid = tid >> 6;
  const int i = blockIdx.x * 256 + tid;
  int v = (i < n) ? (deg[i] + 1) : 0;   // +1 self-loop
  int xv = v;
  #pragma unroll
  for (int off = 1; off < 64; off <<= 1){
    int t = __shfl_up(xv, off);
    if (lane >= off) xv += t;
  }
  if (lane == 63) wsum[wid] = xv;
  __syncthreads();
  int woff = 0, total = 0;
  #pragma unroll
  for (int w = 0; w < 4; ++w){
    int s = wsum[w];
    total += s;
    if (w < wid) woff += s;
  }
  if (i < n) rowp[i] = woff + xv - v;    // local exclusive
  if (tid == 0) bsum[blockIdx.x] = total;
}
__global__ __launch_bounds__(256) void k_scan2(const int* __restrict__ bsum,
    int* __restrict__ boff, int nb){
  __shared__ int wsum[4];
  const int tid = threadIdx.x, lane = tid & 63, wid = tid >> 6;
  int v = (tid < nb) ? bsum[tid] : 0;
  int xv = v;
  #pragma unroll
  for (int off = 1; off < 64; off <<= 1){
    int t = __shfl_up(xv, off);
    if (lane >= off) xv += t;
  }
  if (lane == 63) wsum[wid] = xv;
  __syncthreads();
  int woff = 0, total = 0;
  #pragma unroll
  for (int w = 0; w < 4; ++w){
    int s = wsum[w];
    total += s;
    if (w < wid) woff += s;
  }
  if (tid <= nb) boff[tid] = woff + xv - v;
  if (tid == 0) boff[nb] = total;
}
__global__ void k_scan3(int* __restrict__ rowp, int* __restrict__ cur,
                        const int* __restrict__ boff, int n, int nb){
  int i = blockIdx.x * 256 + threadIdx.x;
  if (i < n){
    int v = rowp[i] + boff[blockIdx.x];
    rowp[i] = v;
    cur[i] = v;
  }
  if (i == 0) rowp[n] = boff[nb];
}

// edges then self-loops in one launch
__global__ void k_fill2(const int* __restrict__ src, const int* __restrict__ dst,
                        int* __restrict__ cur, int* __restrict__ csr, int e, int n){
  int i = blockIdx.x * 256 + threadIdx.x;
  if (i < e){
    int p = atomicAdd(&cur[dst[i]], 1);
    csr[p] = src[i];
  } else if (i < e + n){
    int v = i - e;
    int p = atomicAdd(&cur[v], 1);
    csr[p] = v;
  }
}

// ---------------- x convert: xb[n][96] (bf16, zero-pad) = x[n][74] ----------------
__global__ void k_xconv(const float* __restrict__ x, unsigned short* __restrict__ xb,
                        int n){
  int idx = blockIdx.x * 256 + threadIdx.x;
  int total = n * KPAD;
  if (idx >= total) return;
  int row = idx / KPAD;
  int k = idx - row * KPAD;
  float v = (k < F_IN) ? x[(size_t)row * F_IN + k] : 0.f;
  xb[idx] = f2bf(v);
}

// in_w [74][256] -> Wt_in [256][96] bf16 transposed+padded
__global__ void k_wconv_in(const float* __restrict__ w, unsigned short* __restrict__ Wt){
  int idx = blockIdx.x * 256 + threadIdx.x;
  if (idx >= HDIM * KPAD) return;
  int c = idx / KPAD;
  int k = idx - c * KPAD;
  float v = (k < F_IN) ? w[(size_t)k * HDIM + c] : 0.f;
  Wt[idx] = f2bf(v);
}

// ---------------- input projection via MFMA, K=96, no LDS ----------------
__global__ __launch_bounds__(256) void k_inproj_mfma(
    const unsigned short* __restrict__ xb, const unsigned short* __restrict__ Wt,
    const float* __restrict__ bias, unsigned short* __restrict__ C, int M)
{
  const int l = threadIdx.x & 63;
  const int w = threadIdx.x >> 6;
  const int wm = w >> 1, wn = w & 1;
  const int row0 = blockIdx.x * 128;
  const int col0 = blockIdx.y * 128;

  f32x4 acc[4][4];
  #pragma unroll
  for (int i = 0; i < 4; ++i)
    #pragma unroll
    for (int j = 0; j < 4; ++j) acc[i][j] = (f32x4){0.f, 0.f, 0.f, 0.f};

  #pragma unroll
  for (int kk = 0; kk < 3; ++kk){
    const int kof = kk * 32 + (l >> 4) * 8;
    bf16x8 af[4], bfr[4];
    #pragma unroll
    for (int mi = 0; mi < 4; ++mi){
      int row = row0 + wm * 64 + mi * 16 + (l & 15);
      if (row > M - 1) row = M - 1;
      af[mi] = *(const bf16x8*)(xb + (size_t)row * KPAD + kof);
    }
    #pragma unroll
    for (int ni = 0; ni < 4; ++ni){
      const int col = col0 + wn * 64 + ni * 16 + (l & 15);
      bfr[ni] = *(const bf16x8*)(Wt + (size_t)col * KPAD + kof);
    }
    #pragma unroll
    for (int mi = 0; mi < 4; ++mi)
      #pragma unroll
      for (int ni = 0; ni < 4; ++ni)
        acc[mi][ni] = __builtin_amdgcn_mfma_f32_16x16x32_bf16(
            af[mi], bfr[ni], acc[mi][ni], 0, 0, 0);
  }

  #pragma unroll
  for (int mi = 0; mi < 4; ++mi){
    #pragma unroll
    for (int ni = 0; ni < 4; ++ni){
      const int col = col0 + wn * 64 + ni * 16 + (l & 15);
      const float bv = bias[col];
      #pragma unroll
      for (int r = 0; r < 4; ++r){
        const int row = row0 + wm * 64 + mi * 16 + (l >> 4) * 4 + r;
        if (row < M) C[(size_t)row * HDIM + col] = f2bf(acc[mi][ni][r] + bv);
      }
    }
  }
}

// ---------------- weight convert: Wt[n][k] = (bf16)W[k][n], strided output ----------------
__global__ __launch_bounds__(256) void k_wconv(const float* __restrict__ W,
    unsigned short* __restrict__ Wt, size_t mat_stride){
  __shared__ float tile[32][33];
  const int mat = blockIdx.z;
  const float* Wm = W + (size_t)mat * HDIM * HDIM;
  unsigned short* Wo = Wt + (size_t)mat * mat_stride;
  const int c0 = blockIdx.x * 32, r0 = blockIdx.y * 32;
  const int tx = threadIdx.x & 31, ty = threadIdx.x >> 5;  // 32 x 8
  #pragma unroll
  for (int i = 0; i < 32; i += 8)
    tile[ty + i][tx] = Wm[(size_t)(r0 + ty + i) * HDIM + c0 + tx];
  __syncthreads();
  #pragma unroll
  for (int i = 0; i < 32; i += 8)
    Wo[(size_t)(c0 + ty + i) * HDIM + r0 + tx] = f2bf(tile[tx][ty + i]);
}

// concat biases: bc[layer][512] = [wl_b | wr_b]
__global__ void k_bcat(const float* __restrict__ wl_b, const float* __restrict__ wr_b,
                       float* __restrict__ bc){
  int i = blockIdx.x * 256 + threadIdx.x;
  if (i >= NLAYER * 512) return;
  int layer = i >> 9, c = i & 511;
  bc[i] = (c < 256) ? wl_b[layer * 256 + c] : wr_b[layer * 256 + (c - 256)];
}

// ---------------- MFMA GEMM: C[M,ldc](bf16) = A[M,256](bf16) @ Wt^T + bias ----------------
__global__ __launch_bounds__(256) void k_gemm_mfma(
    const unsigned short* __restrict__ A, const unsigned short* __restrict__ Wt,
    const float* __restrict__ bias, unsigned short* __restrict__ C, int M, int ldc)
{
  __shared__ unsigned short As[2][128 * 64];
  __shared__ unsigned short Bs[2][128 * 64];
  const int tid = threadIdx.x;
  const int l   = tid & 63;
  const int w   = tid >> 6;
  const int wm  = w >> 1, wn = w & 1;
  const int row0 = blockIdx.x * 128;
  const int col0 = blockIdx.y * 128;

  const int srow   = l >> 3;
  const int schunk = l & 7;

  f32x4 acc[4][4];
  #pragma unroll
  for (int i = 0; i < 4; ++i)
    #pragma unroll
    for (int j = 0; j < 4; ++j) acc[i][j] = (f32x4){0.f, 0.f, 0.f, 0.f};

  auto stage = [&](int buf, int k0){
    #pragma unroll
    for (int i = 0; i < 4; ++i){
      const int rloc = w * 32 + i * 8 + srow;
      const int sw   = (schunk ^ (rloc & 7)) * 16;
      int ra = row0 + rloc; if (ra > M - 1) ra = M - 1;
      const char* srcA = (const char*)(A + (size_t)ra * HDIM + k0) + sw;
      GLOAD16(srcA, &As[buf][(w * 32 + i * 8) * 64]);
      const char* srcB = (const char*)(Wt + (size_t)(col0 + rloc) * HDIM + k0) + sw;
      GLOAD16(srcB, &Bs[buf][(w * 32 + i * 8) * 64]);
    }
  };

  auto compute = [&](int buf){
    #pragma unroll
    for (int kk = 0; kk < 2; ++kk){
      bf16x8 af[4], bfr[4];
      #pragma unroll
      for (int mi = 0; mi < 4; ++mi){
        const int row = wm * 64 + mi * 16 + (l & 15);
        const int t   = (kk * 4 + (l >> 4)) ^ (row & 7);
        af[mi] = *(const bf16x8*)((const char*)&As[buf][0] + row * 128 + t * 16);
      }
      #pragma unroll
      for (int ni = 0; ni < 4; ++ni){
        const int nn = wn * 64 + ni * 16 + (l & 15);
        const int t  = (kk * 4 + (l >> 4)) ^ (nn & 7);
        bfr[ni] = *(const bf16x8*)((const char*)&Bs[buf][0] + nn * 128 + t * 16);
      }
      #pragma unroll
      for (int mi = 0; mi < 4; ++mi)
        #pragma unroll
        for (int ni = 0; ni < 4; ++ni)
          acc[mi][ni] = __builtin_amdgcn_mfma_f32_16x16x32_bf16(
              af[mi], bfr[ni], acc[mi][ni], 0, 0, 0);
    }
  };

  stage(0, 0);
  int cur = 0;
  #pragma unroll
  for (int t = 0; t < 4; ++t){
    if (t < 3){
      stage(cur ^ 1, (t + 1) * 64);
      asm volatile("s_waitcnt vmcnt(8)" ::: "memory");
    } else {
      asm volatile("s_waitcnt vmcnt(0)" ::: "memory");
    }
    __builtin_amdgcn_s_barrier();
    compute(cur);
    asm volatile("" ::: "memory");
    __builtin_amdgcn_s_barrier();
    cur ^= 1;
  }

  #pragma unroll
  for (int mi = 0; mi < 4; ++mi){
    #pragma unroll
    for (int ni = 0; ni < 4; ++ni){
      const int col = col0 + wn * 64 + ni * 16 + (l & 15);
      const float bv = bias[col];
      #pragma unroll
      for (int r = 0; r < 4; ++r){
        const int row = row0 + wm * 64 + mi * 16 + (l >> 4) * 4 + r;
        if (row < M) C[(size_t)row * ldc + col] = f2bf(acc[mi][ni][r] + bv);
      }
    }
  }
}

// ---------------- fused GATv2: packed-f32 no-max softmax + LN + relu ----------------
__global__ __launch_bounds__(256) void k_gat(
    const unsigned short* __restrict__ xlr,
    const int* __restrict__ rp, const int* __restrict__ csr,
    const float* __restrict__ att, const float* __restrict__ gb,
    const float* __restrict__ lg, const float* __restrict__ lb,
    const unsigned short* __restrict__ hold, unsigned short* __restrict__ hnew,
    int n, int use_res)
{
  const int node = blockIdx.x * 4 + (threadIdx.x >> 6);
  if (node >= n) return;
  const int lane = threadIdx.x & 63;
  const int elem = lane << 2;
  const int head = lane >> 3;
  float4 attv = *(const float4*)(att + head * HEADD + (elem & 31));
  const f32x2 av01 = {attv.x, attv.y}, av23 = {attv.z, attv.w};
  uint2 ur = *(const uint2*)(xlr + (size_t)node * 512 + 256 + elem);
  const f32x2 r01 = bfpair(ur.x), r23 = bfpair(ur.y);

  f32x2 a01 = {0.f, 0.f}, a23 = {0.f, 0.f};
  float l = 0.f;

  auto edgeq = [&](uint2 uu, f32x2& x01, f32x2& x23)->float{
    x01 = bfpair(uu.x); x23 = bfpair(uu.y);
    f32x2 t01 = x01 + r01, t23 = x23 + r23;
    f32x2 m01 = __builtin_elementwise_max(t01, t01 * SLOPE);
    f32x2 m23 = __builtin_elementwise_max(t23, t23 * SLOPE);
    f32x2 d = m01 * av01 + m23 * av23;
    float p = d.x + d.y;
    p += __shfl_xor(p, 1);
    p += __shfl_xor(p, 2);
    p += __shfl_xor(p, 4);
    return __expf(p);
  };

  const int e0 = rp[node], e1 = rp[node + 1];
  int e = e0;
  for (; e + 4 <= e1; e += 4){
    int s0 = csr[e], s1 = csr[e + 1], s2 = csr[e + 2], s3 = csr[e + 3];
    uint2 u0 = *(const uint2*)(xlr + (size_t)s0 * 512 + elem);
    uint2 u1 = *(const uint2*)(xlr + (size_t)s1 * 512 + elem);
    uint2 u2 = *(const uint2*)(xlr + (size_t)s2 * 512 + elem);
    uint2 u3 = *(const uint2*)(xlr + (size_t)s3 * 512 + elem);
    f32x2 x01_0, x23_0, x01_1, x23_1, x01_2, x23_2, x01_3, x23_3;
    float q0 = edgeq(u0, x01_0, x23_0);
    float q1 = edgeq(u1, x01_1, x23_1);
    float q2 = edgeq(u2, x01_2, x23_2);
    float q3 = edgeq(u3, x01_3, x23_3);
    l += (q0 + q1) + (q2 + q3);
    a01 += q0 * x01_0; a23 += q0 * x23_0;
    a01 += q1 * x01_1; a23 += q1 * x23_1;
    a01 += q2 * x01_2; a23 += q2 * x23_2;
    a01 += q3 * x01_3; a23 += q3 * x23_3;
  }
  for (; e < e1; ++e){
    int s = csr[e];
    uint2 u = *(const uint2*)(xlr + (size_t)s * 512 + elem);
    f32x2 x01, x23;
    float q = edgeq(u, x01, x23);
    l += q;
    a01 += q * x01; a23 += q * x23;
  }

  const float inv = 1.f / l;
  const size_t base = (size_t)node * HDIM + elem;
  float f0 = a01.x * inv + gb[elem + 0];
  float f1 = a01.y * inv + gb[elem + 1];
  float f2 = a23.x * inv + gb[elem + 2];
  float f3 = a23.y * inv + gb[elem + 3];
  if (use_res){
    ushort4 hv = *(const ushort4*)(hold + base);
    f0 += bf2f(hv.x); f1 += bf2f(hv.y); f2 += bf2f(hv.z); f3 += bf2f(hv.w);
  }
  float s = f0 + f1 + f2 + f3;
  #pragma unroll
  for (int off = 1; off < 64; off <<= 1) s += __shfl_xor(s, off);
  const float mean = s * (1.f / HDIM);
  float d0 = f0 - mean, d1 = f1 - mean, d2 = f2 - mean, d3 = f3 - mean;
  float q = d0 * d0 + d1 * d1 + d2 * d2 + d3 * d3;
  #pragma unroll
  for (int off = 1; off < 64; off <<= 1) q += __shfl_xor(q, off);
  const float rs = rsqrtf(q * (1.f / HDIM) + EPSN);
  float o0 = d0 * rs * lg[elem + 0] + lb[elem + 0]; o0 = o0 > 0.f ? o0 : 0.f;
  float o1 = d1 * rs * lg[elem + 1] + lb[elem + 1]; o1 = o1 > 0.f ? o1 : 0.f;
  float o2 = d2 * rs * lg[elem + 2] + lb[elem + 2]; o2 = o2 > 0.f ? o2 : 0.f;
  float o3 = d3 * rs * lg[elem + 3] + lb[elem + 3]; o3 = o3 > 0.f ? o3 : 0.f;
  ushort4 st; st.x = f2bf(o0); st.y = f2bf(o1); st.z = f2bf(o2); st.w = f2bf(o3);
  *(ushort4*)(hnew + base) = st;
}

// ---------------- mean pool: batch sorted -> per-graph segment reduce ----------------
__global__ __launch_bounds__(256) void k_pool2(
    const unsigned short* __restrict__ ho, const int* __restrict__ batch,
    float* __restrict__ gr, int n)
{
  const int g = blockIdx.x;
  int lo = 0, hi = n;
  while (lo < hi){ int mid = (lo + hi) >> 1; if (batch[mid] < g) lo = mid + 1; else hi = mid; }
  const int s = lo;
  hi = n;
  while (lo < hi){ int mid = (lo + hi) >> 1; if (batch[mid] < g + 1) lo = mid + 1; else hi = mid; }
  const int e = lo;
  const int j = threadIdx.x;
  float acc = 0.f;
  for (int i = s; i < e; ++i) acc += bf2f(ho[(size_t)i * HDIM + j]);
  int c = e - s; if (c < 1) c = 1;
  gr[(size_t)g * HDIM + j] = acc / (float)c;
}

// ---------------- tiny MLP ----------------
__global__ void k_fc(const float* __restrict__ in, const float* __restrict__ w,
                     const float* __restrict__ b, float* __restrict__ out,
                     int kin, int kout){
  __shared__ float s[256];
  int g = blockIdx.x, j = threadIdx.x;
  for (int k = j; k < kin; k += blockDim.x) s[k] = in[(size_t)g * kin + k];
  __syncthreads();
  float a = b[j];
  for (int k = 0; k < kin; ++k) a = fmaf(s[k], w[k * kout + j], a);
  out[(size_t)g * kout + j] = a;
}

// fused BN stats + apply + relu: one block per channel
__global__ __launch_bounds__(256) void k_bn(float* __restrict__ z,
    const float* __restrict__ gam, const float* __restrict__ bet, int g_, int c_){
  const int c = blockIdx.x;
  float s = 0.f, s2 = 0.f;
  for (int r = threadIdx.x; r < g_; r += 256){
    float v = z[(size_t)r * c_ + c];
    s += v; s2 += v * v;
  }
  #pragma unroll
  for (int off = 1; off < 64; off <<= 1){ s += __shfl_xor(s, off); s2 += __shfl_xor(s2, off); }
  __shared__ float sw[4], sw2[4];
  __shared__ float smean, srstd;
  int lane = threadIdx.x & 63, wid = threadIdx.x >> 6;
  if (lane == 0){ sw[wid] = s; sw2[wid] = s2; }
  __syncthreads();
  if (threadIdx.x == 0){
    float ts = sw[0] + sw[1] + sw[2] + sw[3];
    float ts2 = sw2[0] + sw2[1] + sw2[2] + sw2[3];
    float mm = ts / g_;
    float vv = ts2 / g_ - mm * mm;
    smean = mm; srstd = rsqrtf(vv + EPSN);
  }
  __syncthreads();
  const float mm = smean, rs = srstd, gg = gam[c], bb = bet[c];
  for (int r = threadIdx.x; r < g_; r += 256){
    float v = (z[(size_t)r * c_ + c] - mm) * rs * gg + bb;
    z[(size_t)r * c_ + c] = v > 0.f ? v : 0.f;
  }
}

__global__ __launch_bounds__(256) void k_out(const float* __restrict__ z,
    const float* __restrict__ w, const float* __restrict__ b,
    float* __restrict__ out, int g_){
  int g = blockIdx.x * 4 + (threadIdx.x >> 6);
  if (g >= g_) return;
  int lane = threadIdx.x & 63;
  float v = z[(size_t)g * 64 + lane] * w[lane];
  #pragma unroll
  for (int off = 1; off < 64; off <<= 1) v += __shfl_xor(v, off);
  if (lane == 0) out[g] = v + b[0];
}

// ---------------- host ----------------
extern "C" void kernel_launch(void* const* d_in, const int* in_sizes, int n_in,
                              void* d_out, int out_size, void* d_ws, size_t ws_size,
                              hipStream_t stream)
{
  const float* x     = (const float*)d_in[0];
  const int*   ei    = (const int*)  d_in[1];
  const int*   batch = (const int*)  d_in[2];
  const float* in_w  = (const float*)d_in[3];
  const float* in_b  = (const float*)d_in[4];
  const float* wl    = (const float*)d_in[5];
  const float* wl_b  = (const float*)d_in[6];
  const float* wr    = (const float*)d_in[7];
  const float* wr_b  = (const float*)d_in[8];
  const float* att   = (const float*)d_in[9];
  const float* gat_b = (const float*)d_in[10];
  const float* ln_g  = (const float*)d_in[11];
  const float* ln_b  = (const float*)d_in[12];
  const float* out_w = (const float*)d_in[13];
  const float* out_b = (const float*)d_in[14];
  const float* p1_w  = (const float*)d_in[15];
  const float* p1_b  = (const float*)d_in[16];
  const float* bn1_g = (const float*)d_in[17];
  const float* bn1_b = (const float*)d_in[18];
  const float* p2_w  = (const float*)d_in[19];
  const float* p2_b  = (const float*)d_in[20];
  const float* bn2_g = (const float*)d_in[21];
  const float* bn2_b = (const float*)d_in[22];
  const float* p3_w  = (const float*)d_in[23];
  const float* p3_b  = (const float*)d_in[24];

  const int n = in_sizes[0] / F_IN;     // 50000
  const int e = in_sizes[1] / 2;        // 800000
  const int g = out_size;               // 500
  const int nb = (n + 255) / 256;

  char* p = (char*)d_ws;
  auto take = [&](size_t bytes)->char*{
    char* q = p; p += ((bytes + 255) & ~(size_t)255); return q;
  };
  unsigned short* hA   = (unsigned short*)take((size_t)n * HDIM * 2);
  unsigned short* hB   = (unsigned short*)take((size_t)n * HDIM * 2);
  unsigned short* xlr  = (unsigned short*)take((size_t)n * 512 * 2);
  unsigned short* WtLR = (unsigned short*)take((size_t)NLAYER * 512 * HDIM * 2);
  unsigned short* WtO  = (unsigned short*)take((size_t)HDIM * HDIM * 2);
  unsigned short* WtI  = (unsigned short*)take((size_t)HDIM * KPAD * 2);
  float* bconc = (float*)take((size_t)NLAYER * 512 * 4);
  int*   deg   = (int*)take((size_t)n * 4);
  int*   rowp  = (int*)take((size_t)(n + 1) * 4);
  int*   cur   = (int*)take((size_t)n * 4);
  int*   csr   = (int*)take((size_t)(e + n) * 4);
  int*   bsum  = (int*)take((size_t)(nb + 1) * 4);
  int*   boff  = (int*)take((size_t)(nb + 1) * 4);
  float* gr    = (float*)take((size_t)g * HDIM * 4);
  float* z1    = (float*)take((size_t)g * 128 * 4);
  float* z2    = (float*)take((size_t)g * 64 * 4);
  unsigned short* xb = xlr;  // alias: xb only needed before first GEMM writes xlr
  (void)ws_size; (void)n_in;

  // CSR build
  hipMemsetAsync(deg, 0, (size_t)n * 4, stream);
  k_hist<<<(e + 255) / 256, 256, 0, stream>>>(ei + e, deg, e);
  k_scan1<<<nb, 256, 0, stream>>>(deg, rowp, bsum, n);
  k_scan2<<<1, 256, 0, stream>>>(bsum, boff, nb);
  k_scan3<<<nb, 256, 0, stream>>>(rowp, cur, boff, n, nb);
  k_fill2<<<(e + n + 255) / 256, 256, 0, stream>>>(ei, ei + e, cur, csr, e, n);

  // weight conversion
  k_wconv<<<dim3(8, 8, 4), 256, 0, stream>>>(wl, WtLR, (size_t)512 * HDIM);
  k_wconv<<<dim3(8, 8, 4), 256, 0, stream>>>(wr, WtLR + (size_t)256 * HDIM, (size_t)512 * HDIM);
  k_wconv<<<dim3(8, 8, 1), 256, 0, stream>>>(out_w, WtO, (size_t)HDIM * HDIM);
  k_wconv_in<<<(HDIM * KPAD + 255) / 256, 256, 0, stream>>>(in_w, WtI);
  k_bcat<<<(NLAYER * 512 + 255) / 256, 256, 0, stream>>>(wl_b, wr_b, bconc);

  // input projection (MFMA, K=96)
  k_xconv<<<((n * KPAD) + 255) / 256, 256, 0, stream>>>(x, xb, n);
  k_inproj_mfma<<<dim3((n + 127) / 128, 2), 256, 0, stream>>>(xb, WtI, in_b, hA, n);

  unsigned short* hcur = hA;
  unsigned short* hnext = hB;
  for (int i = 0; i < NLAYER; ++i){
    k_gemm_mfma<<<dim3((n + 127) / 128, 4), 256, 0, stream>>>(
        hcur, WtLR + (size_t)i * 512 * HDIM, bconc + i * 512, xlr, n, 512);
    k_gat<<<(n + 3) / 4, 256, 0, stream>>>(xlr, rowp, csr,
        att + (size_t)i * NHEAD * HEADD, gat_b + i * HDIM,
        ln_g + i * HDIM, ln_b + i * HDIM, hcur, hnext, n, i > 0 ? 1 : 0);
    unsigned short* t = hcur; hcur = hnext; hnext = t;
  }
  // output projection
  k_gemm_mfma<<<dim3((n + 127) / 128, 2), 256, 0, stream>>>(
      hcur, WtO, out_b, hnext, n, HDIM);

  // pooling
  k_pool2<<<g, 256, 0, stream>>>(hnext, batch, gr, n);

  // MLP head
  k_fc<<<g, 128, 0, stream>>>(gr, p1_w, p1_b, z1, HDIM, 128);
  k_bn<<<128, 256, 0, stream>>>(z1, bn1_g, bn1_b, g, 128);
  k_fc<<<g, 64, 0, stream>>>(z1, p2_w, p2_b, z2, 128, 64);
  k_bn<<<64, 256, 0, stream>>>(z2, bn2_g, bn2_b, g, 64);
  k_out<<<(g + 3) / 4, 256, 0, stream>>>(z2, p3_w, p3_b, (float*)d_out, g);
}

// Round 6
// 682.034 us; speedup vs baseline: 2.5878x; 1.0310x over previous
//
#include <hip/hip_runtime.h>
#include <hip/hip_bf16.h>

#define F_IN   74
#define KPAD   96
#define HDIM   256
#define NHEAD  8
#define HEADD  32
#define NLAYER 4
#define SLOPE  0.2f
#define EPSN   1e-5f

typedef __attribute__((ext_vector_type(8))) short bf16x8;
typedef __attribute__((ext_vector_type(4))) float f32x4;
typedef __attribute__((ext_vector_type(2))) float f32x2;

__device__ __forceinline__ float bf2f(unsigned short u){
  union { unsigned int i; float f; } x; x.i = ((unsigned int)u) << 16; return x.f;
}
__device__ __forceinline__ unsigned short f2bf(float f){
  union { float f; unsigned int i; } x; x.f = f;
  unsigned int u = x.i;
  return (unsigned short)((u + 0x7FFFu + ((u >> 16) & 1u)) >> 16);
}
__device__ __forceinline__ f32x2 bfpair(unsigned int u){
  union { unsigned int i; float f; } lo, hi;
  lo.i = u << 16; hi.i = u & 0xffff0000u;
  return (f32x2){lo.f, hi.f};
}
// sum over 8-lane group via DPP (full-rate VALU, no LDS pipe).
// after xor1+xor2 each quad is uniform, so ROW_HALF_MIRROR completes the 8-sum.
__device__ __forceinline__ float dpp_sum8(float p){
  int t;
  t = __builtin_amdgcn_update_dpp(0, __float_as_int(p), 0xB1, 0xF, 0xF, true);  // quad_perm xor1
  p += __int_as_float(t);
  t = __builtin_amdgcn_update_dpp(0, __float_as_int(p), 0x4E, 0xF, 0xF, true);  // quad_perm xor2
  p += __int_as_float(t);
  t = __builtin_amdgcn_update_dpp(0, __float_as_int(p), 0x141, 0xF, 0xF, true); // row_half_mirror
  p += __int_as_float(t);
  return p;
}

#define GLOAD16(g, s) __builtin_amdgcn_global_load_lds( \
  (const __attribute__((address_space(1))) void*)(g), \
  (__attribute__((address_space(3))) void*)(s), 16, 0, 0)

// ---------------- CSR build (dst-grouped) ----------------
__global__ void k_hist(const int* __restrict__ dst, int* __restrict__ deg, int e){
  int i = blockIdx.x * 256 + threadIdx.x;
  if (i < e) atomicAdd(&deg[dst[i]], 1);
}

__global__ __launch_bounds__(256) void k_scan1(const int* __restrict__ deg,
    int* __restrict__ rowp, int* __restrict__ bsum, int n){
  __shared__ int wsum[4];
  const int tid = threadIdx.x, lane = tid & 63, wid = tid >> 6;
  const int i = blockIdx.x * 256 + tid;
  int v = (i < n) ? (deg[i] + 1) : 0;   // +1 self-loop
  int xv = v;
  #pragma unroll
  for (int off = 1; off < 64; off <<= 1){
    int t = __shfl_up(xv, off);
    if (lane >= off) xv += t;
  }
  if (lane == 63) wsum[wid] = xv;
  __syncthreads();
  int woff = 0, total = 0;
  #pragma unroll
  for (int w = 0; w < 4; ++w){
    int s = wsum[w];
    total += s;
    if (w < wid) woff += s;
  }
  if (i < n) rowp[i] = woff + xv - v;    // local exclusive
  if (tid == 0) bsum[blockIdx.x] = total;
}
__global__ __launch_bounds__(256) void k_scan2(const int* __restrict__ bsum,
    int* __restrict__ boff, int nb){
  __shared__ int wsum[4];
  const int tid = threadIdx.x, lane = tid & 63, wid = tid >> 6;
  int v = (tid < nb) ? bsum[tid] : 0;
  int xv = v;
  #pragma unroll
  for (int off = 1; off < 64; off <<= 1){
    int t = __shfl_up(xv, off);
    if (lane >= off) xv += t;
  }
  if (lane == 63) wsum[wid] = xv;
  __syncthreads();
  int woff = 0, total = 0;
  #pragma unroll
  for (int w = 0; w < 4; ++w){
    int s = wsum[w];
    total += s;
    if (w < wid) woff += s;
  }
  if (tid <= nb) boff[tid] = woff + xv - v;
  if (tid == 0) boff[nb] = total;
}
__global__ void k_scan3(int* __restrict__ rowp, int* __restrict__ cur,
                        const int* __restrict__ boff, int n, int nb){
  int i = blockIdx.x * 256 + threadIdx.x;
  if (i < n){
    int v = rowp[i] + boff[blockIdx.x];
    rowp[i] = v;
    cur[i] = v;
  }
  if (i == 0) rowp[n] = boff[nb];
}

// edges then self-loops in one launch; csr stores BYTE offsets (src*1024)
__global__ void k_fill2(const int* __restrict__ src, const int* __restrict__ dst,
                        int* __restrict__ cur, unsigned int* __restrict__ csr,
                        int e, int n){
  int i = blockIdx.x * 256 + threadIdx.x;
  if (i < e){
    int p = atomicAdd(&cur[dst[i]], 1);
    csr[p] = ((unsigned int)src[i]) << 10;
  } else if (i < e + n){
    int v = i - e;
    int p = atomicAdd(&cur[v], 1);
    csr[p] = ((unsigned int)v) << 10;
  }
}

// ---------------- fused prep: weight transposes + bias concat + x convert ----------------
// blocks [0,576): 32x32 transpose tiles (wl 256, wr 256, out_w 64)
// blocks [576,672): wconv_in elementwise (256*96)
// blocks [672,680): bcat (4*512)
// blocks [680, 680+ceil(n*96/256)): xconv
__global__ __launch_bounds__(256) void k_prep(
    const float* __restrict__ wl, const float* __restrict__ wr,
    const float* __restrict__ out_w, const float* __restrict__ in_w,
    const float* __restrict__ wl_b, const float* __restrict__ wr_b,
    const float* __restrict__ x,
    unsigned short* __restrict__ WtLR, unsigned short* __restrict__ WtO,
    unsigned short* __restrict__ WtI, float* __restrict__ bconc,
    unsigned short* __restrict__ xb, int n)
{
  const int b = blockIdx.x;
  const int tid = threadIdx.x;
  if (b < 576){
    __shared__ float tile[32][33];
    const float* Wm;
    unsigned short* Wo;
    int rem;
    if (b < 512){
      const int matset = b >> 8;        // 0=wl, 1=wr
      const int mat = (b >> 6) & 3;
      rem = b & 63;
      const float* srcw = matset ? wr : wl;
      Wm = srcw + (size_t)mat * HDIM * HDIM;
      Wo = WtLR + (size_t)mat * 512 * HDIM + (matset ? (size_t)256 * HDIM : 0);
    } else {
      rem = b - 512;
      Wm = out_w; Wo = WtO;
    }
    const int c0 = (rem & 7) * 32, r0 = (rem >> 3) * 32;
    const int tx = tid & 31, ty = tid >> 5;
    #pragma unroll
    for (int i = 0; i < 32; i += 8)
      tile[ty + i][tx] = Wm[(size_t)(r0 + ty + i) * HDIM + c0 + tx];
    __syncthreads();
    #pragma unroll
    for (int i = 0; i < 32; i += 8)
      Wo[(size_t)(c0 + ty + i) * HDIM + r0 + tx] = f2bf(tile[tx][ty + i]);
  } else if (b < 672){
    int idx = (b - 576) * 256 + tid;          // < 256*96
    int c = idx / KPAD, k = idx - c * KPAD;
    float v = (k < F_IN) ? in_w[(size_t)k * HDIM + c] : 0.f;
    WtI[idx] = f2bf(v);
  } else if (b < 680){
    int i = (b - 672) * 256 + tid;
    if (i < NLAYER * 512){
      int layer = i >> 9, c = i & 511;
      bconc[i] = (c < 256) ? wl_b[layer * 256 + c] : wr_b[layer * 256 + (c - 256)];
    }
  } else {
    int idx = (b - 680) * 256 + tid;
    if (idx < n * KPAD){
      int row = idx / KPAD, k = idx - row * KPAD;
      float v = (k < F_IN) ? x[(size_t)row * F_IN + k] : 0.f;
      xb[idx] = f2bf(v);
    }
  }
}

// ---------------- input projection via MFMA, K=96, no LDS ----------------
__global__ __launch_bounds__(256) void k_inproj_mfma(
    const unsigned short* __restrict__ xb, const unsigned short* __restrict__ Wt,
    const float* __restrict__ bias, unsigned short* __restrict__ C, int M)
{
  const int l = threadIdx.x & 63;
  const int w = threadIdx.x >> 6;
  const int wm = w >> 1, wn = w & 1;
  const int row0 = blockIdx.x * 128;
  const int col0 = blockIdx.y * 128;

  f32x4 acc[4][4];
  #pragma unroll
  for (int i = 0; i < 4; ++i)
    #pragma unroll
    for (int j = 0; j < 4; ++j) acc[i][j] = (f32x4){0.f, 0.f, 0.f, 0.f};

  #pragma unroll
  for (int kk = 0; kk < 3; ++kk){
    const int kof = kk * 32 + (l >> 4) * 8;
    bf16x8 af[4], bfr[4];
    #pragma unroll
    for (int mi = 0; mi < 4; ++mi){
      int row = row0 + wm * 64 + mi * 16 + (l & 15);
      if (row > M - 1) row = M - 1;
      af[mi] = *(const bf16x8*)(xb + (size_t)row * KPAD + kof);
    }
    #pragma unroll
    for (int ni = 0; ni < 4; ++ni){
      const int col = col0 + wn * 64 + ni * 16 + (l & 15);
      bfr[ni] = *(const bf16x8*)(Wt + (size_t)col * KPAD + kof);
    }
    #pragma unroll
    for (int mi = 0; mi < 4; ++mi)
      #pragma unroll
      for (int ni = 0; ni < 4; ++ni)
        acc[mi][ni] = __builtin_amdgcn_mfma_f32_16x16x32_bf16(
            af[mi], bfr[ni], acc[mi][ni], 0, 0, 0);
  }

  #pragma unroll
  for (int mi = 0; mi < 4; ++mi){
    #pragma unroll
    for (int ni = 0; ni < 4; ++ni){
      const int col = col0 + wn * 64 + ni * 16 + (l & 15);
      const float bv = bias[col];
      #pragma unroll
      for (int r = 0; r < 4; ++r){
        const int row = row0 + wm * 64 + mi * 16 + (l >> 4) * 4 + r;
        if (row < M) C[(size_t)row * HDIM + col] = f2bf(acc[mi][ni][r] + bv);
      }
    }
  }
}

// ---------------- MFMA GEMM: C[M,ldc](bf16) = A[M,256](bf16) @ Wt^T + bias ----------------
__global__ __launch_bounds__(256) void k_gemm_mfma(
    const unsigned short* __restrict__ A, const unsigned short* __restrict__ Wt,
    const float* __restrict__ bias, unsigned short* __restrict__ C, int M, int ldc)
{
  __shared__ unsigned short As[2][128 * 64];
  __shared__ unsigned short Bs[2][128 * 64];
  const int tid = threadIdx.x;
  const int l   = tid & 63;
  const int w   = tid >> 6;
  const int wm  = w >> 1, wn = w & 1;
  const int row0 = blockIdx.x * 128;
  const int col0 = blockIdx.y * 128;

  const int srow   = l >> 3;
  const int schunk = l & 7;

  f32x4 acc[4][4];
  #pragma unroll
  for (int i = 0; i < 4; ++i)
    #pragma unroll
    for (int j = 0; j < 4; ++j) acc[i][j] = (f32x4){0.f, 0.f, 0.f, 0.f};

  auto stage = [&](int buf, int k0){
    #pragma unroll
    for (int i = 0; i < 4; ++i){
      const int rloc = w * 32 + i * 8 + srow;
      const int sw   = (schunk ^ (rloc & 7)) * 16;
      int ra = row0 + rloc; if (ra > M - 1) ra = M - 1;
      const char* srcA = (const char*)(A + (size_t)ra * HDIM + k0) + sw;
      GLOAD16(srcA, &As[buf][(w * 32 + i * 8) * 64]);
      const char* srcB = (const char*)(Wt + (size_t)(col0 + rloc) * HDIM + k0) + sw;
      GLOAD16(srcB, &Bs[buf][(w * 32 + i * 8) * 64]);
    }
  };

  auto compute = [&](int buf){
    #pragma unroll
    for (int kk = 0; kk < 2; ++kk){
      bf16x8 af[4], bfr[4];
      #pragma unroll
      for (int mi = 0; mi < 4; ++mi){
        const int row = wm * 64 + mi * 16 + (l & 15);
        const int t   = (kk * 4 + (l >> 4)) ^ (row & 7);
        af[mi] = *(const bf16x8*)((const char*)&As[buf][0] + row * 128 + t * 16);
      }
      #pragma unroll
      for (int ni = 0; ni < 4; ++ni){
        const int nn = wn * 64 + ni * 16 + (l & 15);
        const int t  = (kk * 4 + (l >> 4)) ^ (nn & 7);
        bfr[ni] = *(const bf16x8*)((const char*)&Bs[buf][0] + nn * 128 + t * 16);
      }
      #pragma unroll
      for (int mi = 0; mi < 4; ++mi)
        #pragma unroll
        for (int ni = 0; ni < 4; ++ni)
          acc[mi][ni] = __builtin_amdgcn_mfma_f32_16x16x32_bf16(
              af[mi], bfr[ni], acc[mi][ni], 0, 0, 0);
    }
  };

  stage(0, 0);
  int cur = 0;
  #pragma unroll
  for (int t = 0; t < 4; ++t){
    if (t < 3){
      stage(cur ^ 1, (t + 1) * 64);
      asm volatile("s_waitcnt vmcnt(8)" ::: "memory");
    } else {
      asm volatile("s_waitcnt vmcnt(0)" ::: "memory");
    }
    __builtin_amdgcn_s_barrier();
    compute(cur);
    asm volatile("" ::: "memory");
    __builtin_amdgcn_s_barrier();
    cur ^= 1;
  }

  #pragma unroll
  for (int mi = 0; mi < 4; ++mi){
    #pragma unroll
    for (int ni = 0; ni < 4; ++ni){
      const int col = col0 + wn * 64 + ni * 16 + (l & 15);
      const float bv = bias[col];
      #pragma unroll
      for (int r = 0; r < 4; ++r){
        const int row = row0 + wm * 64 + mi * 16 + (l >> 4) * 4 + r;
        if (row < M) C[(size_t)row * ldc + col] = f2bf(acc[mi][ni][r] + bv);
      }
    }
  }
}

// ---------------- fused GATv2: DPP-reduce no-max softmax + LN + relu ----------------
__global__ __launch_bounds__(256) void k_gat(
    const unsigned short* __restrict__ xlr,
    const int* __restrict__ rp, const unsigned int* __restrict__ csr,
    const float* __restrict__ att, const float* __restrict__ gb,
    const float* __restrict__ lg, const float* __restrict__ lb,
    const unsigned short* __restrict__ hold, unsigned short* __restrict__ hnew,
    int n, int use_res)
{
  const int node = blockIdx.x * 4 + (threadIdx.x >> 6);
  if (node >= n) return;
  const int lane = threadIdx.x & 63;
  const int elem = lane << 2;
  const int head = lane >> 3;
  float4 attv = *(const float4*)(att + head * HEADD + (elem & 31));
  const f32x2 av01 = {attv.x, attv.y}, av23 = {attv.z, attv.w};
  uint2 ur = *(const uint2*)(xlr + (size_t)node * 512 + 256 + elem);
  const f32x2 r01 = bfpair(ur.x), r23 = bfpair(ur.y);

  // per-lane gather base = xlr + elem (bytes: elem*2); csr holds row byte offsets
  const char* xbase = (const char*)xlr + (elem << 1);

  f32x2 a01 = {0.f, 0.f}, a23 = {0.f, 0.f};
  float l = 0.f;

  auto edgeq = [&](uint2 uu, f32x2& x01, f32x2& x23)->float{
    x01 = bfpair(uu.x); x23 = bfpair(uu.y);
    f32x2 t01 = x01 + r01, t23 = x23 + r23;
    f32x2 m01 = __builtin_elementwise_max(t01, t01 * SLOPE);
    f32x2 m23 = __builtin_elementwise_max(t23, t23 * SLOPE);
    f32x2 d = m01 * av01 + m23 * av23;
    float p = dpp_sum8(d.x + d.y);
    return __expf(p);
  };

  const int e0 = rp[node], e1 = rp[node + 1];
  int e = e0;
  for (; e + 4 <= e1; e += 4){
    unsigned int o0 = csr[e], o1 = csr[e + 1], o2 = csr[e + 2], o3 = csr[e + 3];
    uint2 u0 = *(const uint2*)(xbase + o0);
    uint2 u1 = *(const uint2*)(xbase + o1);
    uint2 u2 = *(const uint2*)(xbase + o2);
    uint2 u3 = *(const uint2*)(xbase + o3);
    f32x2 x01, x23;
    float q0 = edgeq(u0, x01, x23);
    a01 += q0 * x01; a23 += q0 * x23;
    float q1 = edgeq(u1, x01, x23);
    a01 += q1 * x01; a23 += q1 * x23;
    float q2 = edgeq(u2, x01, x23);
    a01 += q2 * x01; a23 += q2 * x23;
    float q3 = edgeq(u3, x01, x23);
    a01 += q3 * x01; a23 += q3 * x23;
    l += (q0 + q1) + (q2 + q3);
  }
  for (; e < e1; ++e){
    unsigned int o = csr[e];
    uint2 u = *(const uint2*)(xbase + o);
    f32x2 x01, x23;
    float q = edgeq(u, x01, x23);
    l += q;
    a01 += q * x01; a23 += q * x23;
  }

  const float inv = 1.f / l;
  const size_t base = (size_t)node * HDIM + elem;
  float f0 = a01.x * inv + gb[elem + 0];
  float f1 = a01.y * inv + gb[elem + 1];
  float f2 = a23.x * inv + gb[elem + 2];
  float f3 = a23.y * inv + gb[elem + 3];
  if (use_res){
    ushort4 hv = *(const ushort4*)(hold + base);
    f0 += bf2f(hv.x); f1 += bf2f(hv.y); f2 += bf2f(hv.z); f3 += bf2f(hv.w);
  }
  float s = f0 + f1 + f2 + f3;
  #pragma unroll
  for (int off = 1; off < 64; off <<= 1) s += __shfl_xor(s, off);
  const float mean = s * (1.f / HDIM);
  float d0 = f0 - mean, d1 = f1 - mean, d2 = f2 - mean, d3 = f3 - mean;
  float q = d0 * d0 + d1 * d1 + d2 * d2 + d3 * d3;
  #pragma unroll
  for (int off = 1; off < 64; off <<= 1) q += __shfl_xor(q, off);
  const float rs = rsqrtf(q * (1.f / HDIM) + EPSN);
  float o0 = d0 * rs * lg[elem + 0] + lb[elem + 0]; o0 = o0 > 0.f ? o0 : 0.f;
  float o1 = d1 * rs * lg[elem + 1] + lb[elem + 1]; o1 = o1 > 0.f ? o1 : 0.f;
  float o2 = d2 * rs * lg[elem + 2] + lb[elem + 2]; o2 = o2 > 0.f ? o2 : 0.f;
  float o3 = d3 * rs * lg[elem + 3] + lb[elem + 3]; o3 = o3 > 0.f ? o3 : 0.f;
  ushort4 st; st.x = f2bf(o0); st.y = f2bf(o1); st.z = f2bf(o2); st.w = f2bf(o3);
  *(ushort4*)(hnew + base) = st;
}

// ---------------- mean pool: batch sorted -> per-graph segment reduce ----------------
__global__ __launch_bounds__(256) void k_pool2(
    const unsigned short* __restrict__ ho, const int* __restrict__ batch,
    float* __restrict__ gr, int n)
{
  const int g = blockIdx.x;
  int lo = 0, hi = n;
  while (lo < hi){ int mid = (lo + hi) >> 1; if (batch[mid] < g) lo = mid + 1; else hi = mid; }
  const int s = lo;
  hi = n;
  while (lo < hi){ int mid = (lo + hi) >> 1; if (batch[mid] < g + 1) lo = mid + 1; else hi = mid; }
  const int e = lo;
  const int j = threadIdx.x;
  float acc = 0.f;
  for (int i = s; i < e; ++i) acc += bf2f(ho[(size_t)i * HDIM + j]);
  int c = e - s; if (c < 1) c = 1;
  gr[(size_t)g * HDIM + j] = acc / (float)c;
}

// ---------------- tiny MLP ----------------
__global__ void k_fc(const float* __restrict__ in, const float* __restrict__ w,
                     const float* __restrict__ b, float* __restrict__ out,
                     int kin, int kout){
  __shared__ float s[256];
  int g = blockIdx.x, j = threadIdx.x;
  for (int k = j; k < kin; k += blockDim.x) s[k] = in[(size_t)g * kin + k];
  __syncthreads();
  float a = b[j];
  for (int k = 0; k < kin; ++k) a = fmaf(s[k], w[k * kout + j], a);
  out[(size_t)g * kout + j] = a;
}

// fused BN stats + apply + relu: one block per channel
__global__ __launch_bounds__(256) void k_bn(float* __restrict__ z,
    const float* __restrict__ gam, const float* __restrict__ bet, int g_, int c_){
  const int c = blockIdx.x;
  float s = 0.f, s2 = 0.f;
  for (int r = threadIdx.x; r < g_; r += 256){
    float v = z[(size_t)r * c_ + c];
    s += v; s2 += v * v;
  }
  #pragma unroll
  for (int off = 1; off < 64; off <<= 1){ s += __shfl_xor(s, off); s2 += __shfl_xor(s2, off); }
  __shared__ float sw[4], sw2[4];
  __shared__ float smean, srstd;
  int lane = threadIdx.x & 63, wid = threadIdx.x >> 6;
  if (lane == 0){ sw[wid] = s; sw2[wid] = s2; }
  __syncthreads();
  if (threadIdx.x == 0){
    float ts = sw[0] + sw[1] + sw[2] + sw[3];
    float ts2 = sw2[0] + sw2[1] + sw2[2] + sw2[3];
    float mm = ts / g_;
    float vv = ts2 / g_ - mm * mm;
    smean = mm; srstd = rsqrtf(vv + EPSN);
  }
  __syncthreads();
  const float mm = smean, rs = srstd, gg = gam[c], bb = bet[c];
  for (int r = threadIdx.x; r < g_; r += 256){
    float v = (z[(size_t)r * c_ + c] - mm) * rs * gg + bb;
    z[(size_t)r * c_ + c] = v > 0.f ? v : 0.f;
  }
}

__global__ __launch_bounds__(256) void k_out(const float* __restrict__ z,
    const float* __restrict__ w, const float* __restrict__ b,
    float* __restrict__ out, int g_){
  int g = blockIdx.x * 4 + (threadIdx.x >> 6);
  if (g >= g_) return;
  int lane = threadIdx.x & 63;
  float v = z[(size_t)g * 64 + lane] * w[lane];
  #pragma unroll
  for (int off = 1; off < 64; off <<= 1) v += __shfl_xor(v, off);
  if (lane == 0) out[g] = v + b[0];
}

// ---------------- host ----------------
extern "C" void kernel_launch(void* const* d_in, const int* in_sizes, int n_in,
                              void* d_out, int out_size, void* d_ws, size_t ws_size,
                              hipStream_t stream)
{
  const float* x     = (const float*)d_in[0];
  const int*   ei    = (const int*)  d_in[1];
  const int*   batch = (const int*)  d_in[2];
  const float* in_w  = (const float*)d_in[3];
  const float* in_b  = (const float*)d_in[4];
  const float* wl    = (const float*)d_in[5];
  const float* wl_b  = (const float*)d_in[6];
  const float* wr    = (const float*)d_in[7];
  const float* wr_b  = (const float*)d_in[8];
  const float* att   = (const float*)d_in[9];
  const float* gat_b = (const float*)d_in[10];
  const float* ln_g  = (const float*)d_in[11];
  const float* ln_b  = (const float*)d_in[12];
  const float* out_w = (const float*)d_in[13];
  const float* out_b = (const float*)d_in[14];
  const float* p1_w  = (const float*)d_in[15];
  const float* p1_b  = (const float*)d_in[16];
  const float* bn1_g = (const float*)d_in[17];
  const float* bn1_b = (const float*)d_in[18];
  const float* p2_w  = (const float*)d_in[19];
  const float* p2_b  = (const float*)d_in[20];
  const float* bn2_g = (const float*)d_in[21];
  const float* bn2_b = (const float*)d_in[22];
  const float* p3_w  = (const float*)d_in[23];
  const float* p3_b  = (const float*)d_in[24];

  const int n = in_sizes[0] / F_IN;     // 50000
  const int e = in_sizes[1] / 2;        // 800000
  const int g = out_size;               // 500
  const int nb = (n + 255) / 256;

  char* p = (char*)d_ws;
  auto take = [&](size_t bytes)->char*{
    char* q = p; p += ((bytes + 255) & ~(size_t)255); return q;
  };
  unsigned short* hA   = (unsigned short*)take((size_t)n * HDIM * 2);
  unsigned short* hB   = (unsigned short*)take((size_t)n * HDIM * 2);
  unsigned short* xlr  = (unsigned short*)take((size_t)n * 512 * 2);
  unsigned short* WtLR = (unsigned short*)take((size_t)NLAYER * 512 * HDIM * 2);
  unsigned short* WtO  = (unsigned short*)take((size_t)HDIM * HDIM * 2);
  unsigned short* WtI  = (unsigned short*)take((size_t)HDIM * KPAD * 2);
  float* bconc = (float*)take((size_t)NLAYER * 512 * 4);
  int*   deg   = (int*)take((size_t)n * 4);
  int*   rowp  = (int*)take((size_t)(n + 1) * 4);
  int*   cur   = (int*)take((size_t)n * 4);
  unsigned int* csr = (unsigned int*)take((size_t)(e + n) * 4);
  int*   bsum  = (int*)take((size_t)(nb + 1) * 4);
  int*   boff  = (int*)take((size_t)(nb + 1) * 4);
  float* gr    = (float*)take((size_t)g * HDIM * 4);
  float* z1    = (float*)take((size_t)g * 128 * 4);
  float* z2    = (float*)take((size_t)g * 64 * 4);
  unsigned short* xb = xlr;  // alias: xb only needed before first GEMM writes xlr
  (void)ws_size; (void)n_in;

  // CSR build
  hipMemsetAsync(deg, 0, (size_t)n * 4, stream);
  k_hist<<<(e + 255) / 256, 256, 0, stream>>>(ei + e, deg, e);
  k_scan1<<<nb, 256, 0, stream>>>(deg, rowp, bsum, n);
  k_scan2<<<1, 256, 0, stream>>>(bsum, boff, nb);
  k_scan3<<<nb, 256, 0, stream>>>(rowp, cur, boff, n, nb);
  k_fill2<<<(e + n + 255) / 256, 256, 0, stream>>>(ei, ei + e, cur, csr, e, n);

  // fused prep (weights, biases, x)
  const int xconv_blocks = (n * KPAD + 255) / 256;
  k_prep<<<680 + xconv_blocks, 256, 0, stream>>>(
      wl, wr, out_w, in_w, wl_b, wr_b, x, WtLR, WtO, WtI, bconc, xb, n);

  // input projection (MFMA, K=96)
  k_inproj_mfma<<<dim3((n + 127) / 128, 2), 256, 0, stream>>>(xb, WtI, in_b, hA, n);

  unsigned short* hcur = hA;
  unsigned short* hnext = hB;
  for (int i = 0; i < NLAYER; ++i){
    k_gemm_mfma<<<dim3((n + 127) / 128, 4), 256, 0, stream>>>(
        hcur, WtLR + (size_t)i * 512 * HDIM, bconc + i * 512, xlr, n, 512);
    k_gat<<<(n + 3) / 4, 256, 0, stream>>>(xlr, rowp, csr,
        att + (size_t)i * NHEAD * HEADD, gat_b + i * HDIM,
        ln_g + i * HDIM, ln_b + i * HDIM, hcur, hnext, n, i > 0 ? 1 : 0);
    unsigned short* t = hcur; hcur = hnext; hnext = t;
  }
  // output projection
  k_gemm_mfma<<<dim3((n + 127) / 128, 2), 256, 0, stream>>>(
      hcur, WtO, out_b, hnext, n, HDIM);

  // pooling
  k_pool2<<<g, 256, 0, stream>>>(hnext, batch, gr, n);

  // MLP head
  k_fc<<<g, 128, 0, stream>>>(gr, p1_w, p1_b, z1, HDIM, 128);
  k_bn<<<128, 256, 0, stream>>>(z1, bn1_g, bn1_b, g, 128);
  k_fc<<<g, 64, 0, stream>>>(z1, p2_w, p2_b, z2, 128, 64);
  k_bn<<<64, 256, 0, stream>>>(z2, bn2_g, bn2_b, g, 64);
  k_out<<<(g + 3) / 4, 256, 0, stream>>>(z2, p3_w, p3_b, (float*)d_out, g);
}